// Round 4
// baseline (2393.031 us; speedup 1.0000x reference)
//
#include <hip/hip_runtime.h>
#include <stdint.h>

// dims fixed by the reference
#define TT 512
#define BB 1024
#define SS 64
#define HH 128
#define TBR (TT*BB)
#define NTILE (TBR/16)     // 32768 16-row MFMA tiles, tile(t,bx) = t*64+bx
#define NPROD 192          // producer blocks in fused kernel
#define NCONS 64           // consumer (scan) blocks

typedef __attribute__((ext_vector_type(8))) short short8;    // 8 x bf16
typedef __attribute__((ext_vector_type(4))) float floatx4;   // MFMA acc
typedef unsigned short u16;
typedef unsigned int u32;
typedef struct { u32 x, y; } u32x2;

struct TrueT  { static constexpr bool value = true;  };
struct FalseT { static constexpr bool value = false; };

__device__ __forceinline__ float bf2f(u16 u){union{u32 i;float f;}v;v.i=((u32)u)<<16;return v.f;}
__device__ __forceinline__ u16 f2bf(float f){union{float f;u32 i;}v;v.f=f;u32 r=v.i+0x7FFFu+((v.i>>16)&1u);return (u16)(r>>16);}
__device__ __forceinline__ float frcp(float x){ return __builtin_amdgcn_rcpf(x); }

// Deterministic dtype detector (R3-proven).
__device__ __forceinline__ bool buf_is_bf16(const u16* p) {
  int ok = 0;
#pragma unroll
  for (int i = 0; i < 32; ++i) {
    u32 v = p[2*i] & 0x7FFFu;
    u32 e = v >> 7;
    ok += (v == 0u || (e >= 96u && e <= 128u)) ? 1 : 0;
  }
  return ok >= 24;
}

template<bool BF> __device__ __forceinline__ float ld1(const void* p, size_t i){
  if constexpr (BF) return bf2f(((const u16*)p)[i]);
  else              return ((const float*)p)[i];
}
__device__ __forceinline__ short8 pack8(floatx4 a, floatx4 b){
  short8 r;
  r[0]=(short)f2bf(a[0]); r[1]=(short)f2bf(a[1]); r[2]=(short)f2bf(a[2]); r[3]=(short)f2bf(a[3]);
  r[4]=(short)f2bf(b[0]); r[5]=(short)f2bf(b[1]); r[6]=(short)f2bf(b[2]); r[7]=(short)f2bf(b[3]);
  return r;
}
template<bool BF> __device__ __forceinline__ short8 ld8(const void* p, size_t i){
  if constexpr (BF) return *(const short8*)((const u16*)p + i);
  else {
    const float* f = (const float*)p + i;
    return pack8(*(const floatx4*)f, *(const floatx4*)(f + 4));
  }
}
template<bool BF> __device__ __forceinline__ void st1(void* p, size_t i, float v){
  if constexpr (BF) ((u16*)p)[i] = f2bf(v);
  else              ((float*)p)[i] = v;
}

// LDS-only barrier (R4-proven): lgkmcnt(0)+s_barrier, no vmcnt drain.
__device__ __forceinline__ void barrier_lds() {
  __asm__ __volatile__("" ::: "memory");
  __builtin_amdgcn_s_waitcnt(0xC07F);
  __builtin_amdgcn_s_barrier();
  __asm__ __volatile__("" ::: "memory");
}
// full drain barrier: vmcnt(0) + lgkmcnt(0) + s_barrier
__device__ __forceinline__ void barrier_full() {
  __asm__ __volatile__("" ::: "memory");
  __builtin_amdgcn_s_waitcnt(0x0070);
  __builtin_amdgcn_s_barrier();
  __asm__ __volatile__("" ::: "memory");
}

__device__ __forceinline__ void wait_flag(const u32* f){
  while (__hip_atomic_load(f, __ATOMIC_ACQUIRE, __HIP_MEMORY_SCOPE_AGENT) == 0u)
    __builtin_amdgcn_s_sleep(8);
}

// A-fragment-ordered LDS index for v_mfma_f32_16x16x32_bf16 (R3/R4-proven).
__device__ __forceinline__ int fragidx(int m,int k){
  return ((k>>5)<<9)+((m+(((k>>3)&3)<<4))<<3)+(k&7);
}
__device__ __forceinline__ floatx4 mfma(short8 a, short8 b, floatx4 c){
  return __builtin_amdgcn_mfma_f32_16x16x32_bf16(a,b,c,0,0,0);
}

// ---------------------------------------------------------------------------
// MLP body: h2 = relu(W2@relu(W1@x+b1)+b2), tiles tau = p, p+NPROD, ...
// Output in MFMA A-frag layout (4KB/tile). FL: release per-tile ready flags
// (immediate for j=0 so consumers warm up fast; batched x4 after to amortize
// the agent-scope release). Flag range computed arithmetically (no scratch).
// ---------------------------------------------------------------------------
template<bool BF, bool FL>
__device__ __forceinline__ void mlp_body(
    const void* __restrict__ x,
    const void* __restrict__ W1, const void* __restrict__ b1,
    const void* __restrict__ W2, const void* __restrict__ b2,
    u16* __restrict__ h2g, u32* __restrict__ flags,
    int p, u16* h1f, u16* h2f)
{
  const int tid = threadIdx.x, lane = tid & 63, wv = tid >> 6;
  const int n16 = lane & 15, q = lane >> 4;
  const int jj = 16*wv + n16;

  short8 w1f[2], w2f[4];
  float b1v, b2v;
#pragma unroll
  for (int ks = 0; ks < 2; ++ks) w1f[ks] = ld8<BF>(W1, (size_t)jj*SS + ks*32 + q*8);
  b1v = ld1<BF>(b1, jj);
#pragma unroll
  for (int ks = 0; ks < 4; ++ks) w2f[ks] = ld8<BF>(W2, (size_t)jj*HH + ks*32 + q*8);
  b2v = ld1<BF>(b2, jj);

  int jflag = 0;   // first j whose flag is not yet stored
  int j = 0;
  for (int tau = p; tau < NTILE; tau += NPROD, ++j) {
    short8 xc0, xc1;
    {
      size_t base = ((size_t)tau*16 + n16)*SS + q*8;
      if constexpr (BF) {
        xc0 = *(const short8*)((const u16*)x + base);
        xc1 = *(const short8*)((const u16*)x + base + 32);
      } else {
        const float* f = (const float*)x + base;
        xc0 = pack8(*(const floatx4*)f, *(const floatx4*)(f+4));
        xc1 = pack8(*(const floatx4*)(f+32), *(const floatx4*)(f+36));
      }
    }
    floatx4 a = {0.f,0.f,0.f,0.f};
    a = mfma(xc0, w1f[0], a);
    a = mfma(xc1, w1f[1], a);
#pragma unroll
    for (int r = 0; r < 4; ++r) {
      float v = a[r] + b1v; v = v > 0.f ? v : 0.f;
      h1f[fragidx(4*q + r, jj)] = f2bf(v);
    }
    barrier_lds();
    short8 h1a[4];
#pragma unroll
    for (int ks = 0; ks < 4; ++ks) h1a[ks] = *(const short8*)(h1f + ks*512 + lane*8);
    floatx4 a2 = {0.f,0.f,0.f,0.f};
#pragma unroll
    for (int ks = 0; ks < 4; ++ks) a2 = mfma(h1a[ks], w2f[ks], a2);
#pragma unroll
    for (int r = 0; r < 4; ++r) {
      float v = a2[r] + b2v; v = v > 0.f ? v : 0.f;
      h2f[fragidx(4*q + r, jj)] = f2bf(v);
    }
    barrier_lds();
    u32x2 v2 = *(const u32x2*)(h2f + tid*4);
    *(u32x2*)(h2g + (size_t)tau*2048 + tid*4) = v2;
    if constexpr (FL) {
      barrier_full();                       // all waves' stores drained to L2
      bool flush = (j == 0) || ((j & 3) == 3) || (tau + NPROD >= NTILE);
      if (flush) {
        if (tid == 0) {
          __builtin_amdgcn_fence(__ATOMIC_RELEASE, "agent");   // L2 writeback
          for (int i = jflag; i <= j; ++i)
            __hip_atomic_store(flags + (size_t)p + (size_t)NPROD*i, 1u,
                               __ATOMIC_RELAXED, __HIP_MEMORY_SCOPE_AGENT);
        }
        jflag = j + 1;
      }
    } else {
      barrier_lds();
    }
  }
}

// ---------------------------------------------------------------------------
// Scan body (R6-proven): GRU recurrence, MLP removed. Per step: haf LDS
// reads, stage3 (Wih on h2 A-frag streamed from global, 2-step reg
// prefetch), rec, heads, ONE barrier. FL: producer-consumer flag gating,
// flag load software-pipelined one step ahead (latency hidden in the
// 2-step refill slack); acquire fence only until all tiles ready.
// ---------------------------------------------------------------------------
template<bool BF, bool FL>
__device__ __forceinline__ void scan_body(
    const void* __restrict__ done_, const void* __restrict__ gstate,
    const void* __restrict__ Wih, const void* __restrict__ bih,
    const void* __restrict__ Whh, const void* __restrict__ bhh,
    const void* __restrict__ Wa, const void* __restrict__ ba,
    const void* __restrict__ Wc, const void* __restrict__ bc,
    const u16* __restrict__ h2g, const u32* __restrict__ flags,
    float* __restrict__ lgws, float* __restrict__ vws,
    void* __restrict__ out, int bx, u16 (*hbuf)[2048])
{
  const int tid = threadIdx.x, lane = tid & 63, wv = tid >> 6;
  const int n16 = lane & 15, q = lane >> 4;
  const int b0 = bx * 16;
  const int jj = 16*wv + n16;

  // ---- weights -> register B-fragments ---------------------------------
  short8 wif[3][4], whf[3][4], scf[4];
  float bihv2, bhv2, bb0, bb1;
  {
    float bi0, bi1, bh0, bh1;
#pragma unroll
    for (int g = 0; g < 3; ++g) {
      int grow = g*128 + jj;
#pragma unroll
      for (int ks = 0; ks < 4; ++ks) {
        wif[g][ks] = ld8<BF>(Wih, (size_t)grow*HH + ks*32 + q*8);
        whf[g][ks] = ld8<BF>(Whh, (size_t)grow*HH + ks*32 + q*8);
      }
      float bi = ld1<BF>(bih, grow), bh = ld1<BF>(bhh, grow);
      if (g == 0) { bi0 = bi; bh0 = bh; }
      else if (g == 1) { bi1 = bi; bh1 = bh; }
      else { bihv2 = bi; bhv2 = bh; }
    }
    bb0 = bi0 + bh0;
    bb1 = bi1 + bh1;
  }
  if (wv == 1) {
#pragma unroll
    for (int ks = 0; ks < 4; ++ks) scf[ks] = ld8<BF>(Wa, (size_t)n16*HH + ks*32 + q*8);
  } else if (wv == 2) {
#pragma unroll
    for (int ks = 0; ks < 4; ++ks) {
      short8 z = {0,0,0,0,0,0,0,0};
      if (n16 == 0) z = ld8<BF>(Wc, (size_t)ks*32 + q*8);
      scf[ks] = z;
    }
  } else {
#pragma unroll
    for (int ks = 0; ks < 4; ++ks) { short8 z = {0,0,0,0,0,0,0,0}; scf[ks] = z; }
  }
  const float bav = ld1<BF>(ba, n16);
  const float bcv = ld1<BF>(bc, 0);

  // ---- h0 state --------------------------------------------------------
  float hreg[4];
#pragma unroll
  for (int r = 0; r < 4; ++r) {
    hreg[r] = ld1<BF>(gstate, (size_t)(b0 + 4*q + r)*HH + jj);
    hbuf[0][fragidx(4*q + r, jj)] = f2bf(hreg[r]);
  }
  float s4cur[2][4];
#pragma unroll
  for (int s = 0; s < 2; ++s)
#pragma unroll
    for (int r = 0; r < 4; ++r)
      s4cur[s][r] = 1.f - ld1<BF>(done_, (size_t)s*BB + b0 + 4*q + r);
  u32x2 draw[2];  floatx4 fdraw[2];
#pragma unroll
  for (int s = 0; s < 2; ++s) { draw[s].x = draw[s].y = 0; fdraw[s] = floatx4{0,0,0,0}; }

  // ---- producer gating for the initial tiles ---------------------------
  if constexpr (FL) {
    wait_flag(flags + (size_t)0*NCONS + bx);
    wait_flag(flags + (size_t)1*NCONS + bx);
    wait_flag(flags + (size_t)2*NCONS + bx);
  }
  u32 fcur = 1; bool allr = !FL;
  if constexpr (FL)
    fcur = __hip_atomic_load(flags + (size_t)3*NCONS + bx, __ATOMIC_RELAXED,
                             __HIP_MEMORY_SCOPE_AGENT);

  // ---- h2 frag prefetch (2-deep register double buffer) ----------------
  const u16* const hz = h2g + (size_t)bx*2048;      // tile(t) = t*64 + bx
  short8 h2p[2][4];
#pragma unroll
  for (int ks = 0; ks < 4; ++ks)
    h2p[0][ks] = *(const short8*)(hz + (size_t)0*64*2048 + ks*512 + lane*8);
#pragma unroll
  for (int ks = 0; ks < 4; ++ks)
    h2p[1][ks] = *(const short8*)(hz + (size_t)1*64*2048 + ks*512 + lane*8);
  floatx4 pipe[3];
#pragma unroll
  for (int g = 0; g < 3; ++g) {            // stage3(tile 0) -> pipe for rec(0)
    floatx4 a = {0.f,0.f,0.f,0.f};
#pragma unroll
    for (int ks = 0; ks < 4; ++ks) a = mfma(h2p[0][ks], wif[g][ks], a);
    pipe[g] = a;
  }
#pragma unroll
  for (int ks = 0; ks < 4; ++ks)           // tile 2 into buffer 0
    h2p[0][ks] = *(const short8*)(hz + (size_t)2*64*2048 + ks*512 + lane*8);
  __syncthreads();

  u16* hw0 = &hbuf[1][0] + fragidx(4*q, jj);   // even step writes hbuf[1]
  u16* hw1 = &hbuf[0][0] + fragidx(4*q, jj);   // odd  step writes hbuf[0]

  for (int t0 = 0; t0 < TT; t0 += 2) {
#pragma unroll
    for (int s = 0; s < 2; ++s) {
      const int t = t0 + s;
      const int pw = s;                    // t0 even => t&1 == s (static!)
      const int pb = s ^ 1;                // (t+1)&1 -- h2p buffer parity

      // 1) critical h reads first
      short8 haf[4];
#pragma unroll
      for (int ks = 0; ks < 4; ++ks)
        haf[ks] = *(const short8*)(&hbuf[pw][0] + ks*512 + lane*8);

      // 2) stage3: gx(tile t+1) from h2p[pb] (fills haf read latency)
      floatx4 pn[3];
#pragma unroll
      for (int g = 0; g < 3; ++g) {
        floatx4 a = {0.f,0.f,0.f,0.f};
#pragma unroll
        for (int ks = 0; ks < 4; ++ks) a = mfma(h2p[pb][ks], wif[g][ks], a);
        pn[g] = a;
      }
      // 3) refill: tile t+3 (clamped; redundant at tail, never consumed)
      {
        const int tl = (t+3 < TT) ? t+3 : TT-1;
        if constexpr (FL) {
          if (!allr) {
            if (fcur) {
              __builtin_amdgcn_fence(__ATOMIC_ACQUIRE, "agent");
            } else {
              wait_flag(flags + (size_t)tl*NCONS + bx);
            }
            if (t+3 >= TT-1) allr = true;
            const int tn = (t+4 < TT) ? t+4 : TT-1;
            fcur = __hip_atomic_load(flags + (size_t)tn*NCONS + bx,
                                     __ATOMIC_RELAXED, __HIP_MEMORY_SCOPE_AGENT);
          }
        }
        const u16* tp = hz + (size_t)tl*64*2048;
#pragma unroll
        for (int ks = 0; ks < 4; ++ks)
          h2p[pb][ks] = *(const short8*)(tp + ks*512 + lane*8);
      }

      // 4) head for t-1 (fire-and-forget)
      if (t > 0 && (wv == 1 || wv == 2)) {
        floatx4 a = {0.f,0.f,0.f,0.f};
#pragma unroll
        for (int ks = 0; ks < 4; ++ks) a = mfma(haf[ks], scf[ks], a);
        if (wv == 1) {
#pragma unroll
          for (int r = 0; r < 4; ++r)
            lgws[((size_t)(t-1)*BB + b0 + 4*q + r)*16 + n16] = a[r] + bav;
        } else if (n16 == 0) {
#pragma unroll
          for (int r = 0; r < 4; ++r)
            vws[(size_t)(t-1)*BB + b0 + 4*q + r] = a[r] + bcv;
        }
      }

      // 5) recurrence step t
      floatx4 agh[3];
#pragma unroll
      for (int g = 0; g < 3; ++g) {
        floatx4 a = {0.f,0.f,0.f,0.f};
#pragma unroll
        for (int ks = 0; ks < 4; ++ks) a = mfma(haf[ks], whf[g][ks], a);
        agh[g] = a;
      }
      u16* hw = pw ? hw1 : hw0;
#pragma unroll
      for (int r = 0; r < 4; ++r) {
        float s4 = s4cur[s][r];
        float tr = pipe[0][r] + __builtin_fmaf(s4, agh[0][r], bb0);
        float tz = pipe[1][r] + __builtin_fmaf(s4, agh[1][r], bb1);
        float xn_ = pipe[2][r] + bihv2;
        float hn_ = __builtin_fmaf(s4, agh[2][r], bhv2);
        float rg = frcp(1.f + __expf(-tr));
        float zg = frcp(1.f + __expf(-tz));
        float ni = __builtin_fmaf(rg, hn_, xn_);
        float ng = __builtin_fmaf(2.f, frcp(1.f + __expf(-2.f*ni)), -1.f);  // tanh
        float hold = hreg[r] * s4;
        float hnew = __builtin_fmaf(zg, hold - ng, ng);
        hreg[r] = hnew;
        hw[r*8] = f2bf(hnew);
      }

      // 6) done prefetch (per 2 steps; clamped at tail)
      if (s == 0) {
#pragma unroll
        for (int ss = 0; ss < 2; ++ss) {
          const int tl = (t0+2+ss < TT) ? t0+2+ss : TT-1;
          size_t didx = (size_t)tl*BB + b0 + 4*q;
          if constexpr (BF) draw[ss] = *(const u32x2*)((const u16*)done_ + didx);
          else              fdraw[ss] = *(const floatx4*)((const float*)done_ + didx);
        }
      }

      barrier_lds();                        // the ONE barrier per step
      // 7) rotate gx pipe
#pragma unroll
      for (int g = 0; g < 3; ++g) pipe[g] = pn[g];
    }
    // rotate done regs (tail values unused)
    if constexpr (BF) {
#pragma unroll
      for (int ss = 0; ss < 2; ++ss) {
        s4cur[ss][0] = 1.f - bf2f((u16)(draw[ss].x & 0xFFFF));
        s4cur[ss][1] = 1.f - bf2f((u16)(draw[ss].x >> 16));
        s4cur[ss][2] = 1.f - bf2f((u16)(draw[ss].y & 0xFFFF));
        s4cur[ss][3] = 1.f - bf2f((u16)(draw[ss].y >> 16));
      }
    } else {
#pragma unroll
      for (int ss = 0; ss < 2; ++ss)
#pragma unroll
        for (int r = 0; r < 4; ++r) s4cur[ss][r] = 1.f - fdraw[ss][r];
    }
  }

  // epilogue: head for t=511 (h_511 in hbuf[0]) + h_last output
  {
    if (wv == 1 || wv == 2) {
      short8 haf[4];
#pragma unroll
      for (int ks = 0; ks < 4; ++ks) haf[ks] = *(const short8*)(&hbuf[0][0] + ks*512 + lane*8);
      floatx4 a = {0.f,0.f,0.f,0.f};
#pragma unroll
      for (int ks = 0; ks < 4; ++ks) a = mfma(haf[ks], scf[ks], a);
      if (wv == 1) {
#pragma unroll
        for (int r = 0; r < 4; ++r)
          lgws[((size_t)(TT-1)*BB + b0 + 4*q + r)*16 + n16] = a[r] + bav;
      } else if (n16 == 0) {
#pragma unroll
        for (int r = 0; r < 4; ++r)
          vws[(size_t)(TT-1)*BB + b0 + 4*q + r] = a[r] + bcv;
      }
    }
#pragma unroll
    for (int r = 0; r < 4; ++r)
      st1<BF>(out, (size_t)3*TBR + (size_t)(b0 + 4*q + r)*HH + jj, hreg[r]);
  }
}

// ---------------------------------------------------------------------------
// FUSED kernel (R7/R8): blocks 0..191 = MLP producers, 192..255 = scan
// consumers. 256 blocks, grid <= 1 block/CU capacity => all co-resident at
// dispatch, no deadlock. Producers cover t-slices ahead of the scan's
// consumption rate after a few-us warmup; the old k_mlp serial phase
// disappears under the scan.
// ---------------------------------------------------------------------------
template<bool BF>
__global__ __launch_bounds__(512, 2) void k_fused(
    const void* __restrict__ x, const void* __restrict__ done_,
    const void* __restrict__ gstate,
    const void* __restrict__ W1, const void* __restrict__ b1,
    const void* __restrict__ W2, const void* __restrict__ b2,
    const void* __restrict__ Wih, const void* __restrict__ bih,
    const void* __restrict__ Whh, const void* __restrict__ bhh,
    const void* __restrict__ Wa, const void* __restrict__ ba,
    const void* __restrict__ Wc, const void* __restrict__ bc,
    u16* __restrict__ h2g, u32* __restrict__ flags,
    float* __restrict__ lgws, float* __restrict__ vws,
    void* __restrict__ out)
{
  if (buf_is_bf16((const u16*)W1) != BF) return;
  __shared__ __align__(16) u16 hbuf[2][2048];
  __shared__ __align__(16) u16 h1f[2048];
  __shared__ __align__(16) u16 h2f[2048];
  if (blockIdx.x < NPROD) {
    mlp_body<BF, true>(x, W1, b1, W2, b2, h2g, flags, blockIdx.x, h1f, h2f);
    return;
  }
  scan_body<BF, true>(done_, gstate, Wih, bih, Whh, bhh, Wa, ba, Wc, bc,
                      h2g, flags, lgws, vws, out, blockIdx.x - NPROD, hbuf);
}

// ---------------------------------------------------------------------------
// Fallback split path (R6): separate MLP + scan kernels (no flags).
// ---------------------------------------------------------------------------
template<bool BF>
__global__ __launch_bounds__(512, 2) void k_mlp(
    const void* __restrict__ x,
    const void* __restrict__ W1, const void* __restrict__ b1,
    const void* __restrict__ W2, const void* __restrict__ b2,
    u16* __restrict__ h2g)
{
  if (buf_is_bf16((const u16*)W1) != BF) return;
  __shared__ __align__(16) u16 h1f[2048];
  __shared__ __align__(16) u16 h2f[2048];
  mlp_body<BF, false>(x, W1, b1, W2, b2, h2g, nullptr, blockIdx.x, h1f, h2f);
}

template<bool BF>
__global__ __launch_bounds__(512, 2) void k_scan_split(
    const void* __restrict__ done_, const void* __restrict__ gstate,
    const void* __restrict__ Wih, const void* __restrict__ bih,
    const void* __restrict__ Whh, const void* __restrict__ bhh,
    const void* __restrict__ Wa, const void* __restrict__ ba,
    const void* __restrict__ Wc, const void* __restrict__ bc,
    const void* __restrict__ W1,                   // dtype detector only
    const u16* __restrict__ h2g,
    float* __restrict__ lgws, float* __restrict__ vws,
    void* __restrict__ out)
{
  if (buf_is_bf16((const u16*)W1) != BF) return;
  __shared__ __align__(16) u16 hbuf[2][2048];
  scan_body<BF, false>(done_, gstate, Wih, bih, Whh, bhh, Wa, ba, Wc, bc,
                       h2g, nullptr, lgws, vws, out, blockIdx.x, hbuf);
}

// ---------------------------------------------------------------------------
// Deep fallback (R5 mono) if workspace can't hold h2g.
// ---------------------------------------------------------------------------
template<bool BF>
__global__ __launch_bounds__(512, 2) void k_scan_mono(
    const void* __restrict__ x, const void* __restrict__ done_,
    const void* __restrict__ gstate,
    const void* __restrict__ W1, const void* __restrict__ b1,
    const void* __restrict__ W2, const void* __restrict__ b2,
    const void* __restrict__ Wih, const void* __restrict__ bih,
    const void* __restrict__ Whh, const void* __restrict__ bhh,
    const void* __restrict__ Wa, const void* __restrict__ ba,
    const void* __restrict__ Wc, const void* __restrict__ bc,
    float* __restrict__ lgws, float* __restrict__ vws,
    void* __restrict__ out)
{
  if (buf_is_bf16((const u16*)W1) != BF) return;

  const int tid = threadIdx.x, lane = tid & 63, wv = tid >> 6;
  const int n16 = lane & 15, q = lane >> 4;
  const int b0 = blockIdx.x * 16;
  const int jj = 16*wv + n16;

  __shared__ __align__(16) u16 hbuf[2][2048];
  __shared__ __align__(16) u16 h1f[2][2048];
  __shared__ __align__(16) u16 h2f[2][2048];

  short8 w1f[2], w2f[4], wif[3][4], whf[3][4], scf[4];
  float b1v, b2v, bihv2, bhv2, bb0, bb1;
  {
    int row = wv*16 + n16;
#pragma unroll
    for (int ks = 0; ks < 2; ++ks) w1f[ks] = ld8<BF>(W1, (size_t)row*SS + ks*32 + q*8);
    b1v = ld1<BF>(b1, row);
#pragma unroll
    for (int ks = 0; ks < 4; ++ks) w2f[ks] = ld8<BF>(W2, (size_t)row*HH + ks*32 + q*8);
    b2v = ld1<BF>(b2, row);
    float bi0, bi1, bh0, bh1;
#pragma unroll
    for (int g = 0; g < 3; ++g) {
      int grow = g*128 + jj;
#pragma unroll
      for (int ks = 0; ks < 4; ++ks) {
        wif[g][ks] = ld8<BF>(Wih, (size_t)grow*HH + ks*32 + q*8);
        whf[g][ks] = ld8<BF>(Whh, (size_t)grow*HH + ks*32 + q*8);
      }
      float bi = ld1<BF>(bih, grow), bh = ld1<BF>(bhh, grow);
      if (g == 0) { bi0 = bi; bh0 = bh; }
      else if (g == 1) { bi1 = bi; bh1 = bh; }
      else { bihv2 = bi; bhv2 = bh; }
    }
    bb0 = bi0 + bh0;
    bb1 = bi1 + bh1;
  }
  if (wv == 1) {
#pragma unroll
    for (int ks = 0; ks < 4; ++ks) scf[ks] = ld8<BF>(Wa, (size_t)n16*HH + ks*32 + q*8);
  } else if (wv == 2) {
#pragma unroll
    for (int ks = 0; ks < 4; ++ks) {
      short8 z = {0,0,0,0,0,0,0,0};
      if (n16 == 0) z = ld8<BF>(Wc, (size_t)ks*32 + q*8);
      scf[ks] = z;
    }
  } else {
#pragma unroll
    for (int ks = 0; ks < 4; ++ks) { short8 z = {0,0,0,0,0,0,0,0}; scf[ks] = z; }
  }
  const float bav = ld1<BF>(ba, n16);
  const float bcv = ld1<BF>(bc, 0);

  float hreg[4];
#pragma unroll
  for (int r = 0; r < 4; ++r) {
    hreg[r] = ld1<BF>(gstate, (size_t)(b0 + 4*q + r)*HH + jj);
    hbuf[0][fragidx(4*q + r, jj)] = f2bf(hreg[r]);
  }
  short8 xc[2][2], xn[2][2];
#pragma unroll
  for (int s = 0; s < 2; ++s)
#pragma unroll
    for (int ks = 0; ks < 2; ++ks)
      xc[s][ks] = ld8<BF>(x, ((size_t)s*BB + b0 + n16)*SS + ks*32 + q*8);
  float s4cur[2][4];
#pragma unroll
  for (int s = 0; s < 2; ++s)
#pragma unroll
    for (int r = 0; r < 4; ++r) s4cur[s][r] = 1.f;
  u32x2 draw[2];  floatx4 fdraw[2];
#pragma unroll
  for (int s = 0; s < 2; ++s) { draw[s].x = draw[s].y = 0; fdraw[s] = floatx4{0,0,0,0}; }
#pragma unroll
  for (int s = 0; s < 2; ++s)
#pragma unroll
    for (int ks = 0; ks < 2; ++ks) { short8 z={0,0,0,0,0,0,0,0}; xn[s][ks]=z; }
  floatx4 pipe[2][3];
#pragma unroll
  for (int s = 0; s < 2; ++s)
#pragma unroll
    for (int g = 0; g < 3; ++g) pipe[s][g] = floatx4{0.f,0.f,0.f,0.f};
  __syncthreads();

  u16* hw0 = &hbuf[1][0] + fragidx(4*q, jj);
  u16* hw1 = &hbuf[0][0] + fragidx(4*q, jj);

  auto iter = [&](int t0, auto steady) {
    constexpr bool ST = decltype(steady)::value;
#pragma unroll
    for (int s = 0; s < 2; ++s) {
      const int t = t0 + s;
      const bool s1on = ST || (t <= TT-5);
      const bool s2on = ST || (t >= -3 && t <= TT-4);
      const bool s3on = ST || (t >= -2 && t <= TT-3);
      const bool ron  = ST || (t >= 0);
      const int pw = t & 1;

      short8 haf[4];
      if (ron) {
#pragma unroll
        for (int ks = 0; ks < 4; ++ks)
          haf[ks] = *(const short8*)(&hbuf[pw][0] + ks*512 + lane*8);
      }
      if (s1on) {
        floatx4 a = {0.f,0.f,0.f,0.f};
        a = mfma(xc[s][0], w1f[0], a);
        a = mfma(xc[s][1], w1f[1], a);
#pragma unroll
        for (int r = 0; r < 4; ++r) {
          float v = a[r] + b1v; v = v > 0.f ? v : 0.f;
          h1f[pw][fragidx(4*q + r, jj)] = f2bf(v);
        }
      }
      if (s2on) {
        short8 h1a[4];
#pragma unroll
        for (int ks = 0; ks < 4; ++ks)
          h1a[ks] = *(const short8*)(&h1f[pw^1][0] + ks*512 + lane*8);
        floatx4 a = {0.f,0.f,0.f,0.f};
#pragma unroll
        for (int ks = 0; ks < 4; ++ks) a = mfma(h1a[ks], w2f[ks], a);
#pragma unroll
        for (int r = 0; r < 4; ++r) {
          float v = a[r] + b2v; v = v > 0.f ? v : 0.f;
          h2f[pw][fragidx(4*q + r, jj)] = f2bf(v);
        }
      }
      if (s == 0) {
        if (ST || (t0 + 6 < TT)) {
          if constexpr (BF) {
#pragma unroll
            for (int ss = 0; ss < 2; ++ss) {
              size_t base = ((size_t)(t0+6+ss)*BB + b0 + n16)*SS + q*8;
              xn[ss][0] = *(const short8*)((const u16*)x + base);
              xn[ss][1] = *(const short8*)((const u16*)x + base + 32);
            }
          }
        }
        if (ST || (t0+2 >= 0 && t0+2 < TT)) {
#pragma unroll
          for (int ss = 0; ss < 2; ++ss) {
            size_t didx = (size_t)(t0+2+ss)*BB + b0 + 4*q;
            if constexpr (BF) draw[ss] = *(const u32x2*)((const u16*)done_ + didx);
            else              fdraw[ss] = *(const floatx4*)((const float*)done_ + didx);
          }
        }
      }
      if (ron) {
        if (t > 0 && (wv == 1 || wv == 2)) {
          floatx4 a = {0.f,0.f,0.f,0.f};
#pragma unroll
          for (int ks = 0; ks < 4; ++ks) a = mfma(haf[ks], scf[ks], a);
          if (wv == 1) {
#pragma unroll
            for (int r = 0; r < 4; ++r)
              lgws[((size_t)(t-1)*BB + b0 + 4*q + r)*16 + n16] = a[r] + bav;
          } else if (n16 == 0) {
#pragma unroll
            for (int r = 0; r < 4; ++r)
              vws[(size_t)(t-1)*BB + b0 + 4*q + r] = a[r] + bcv;
          }
        }
        floatx4 agh[3];
#pragma unroll
        for (int g = 0; g < 3; ++g) {
          floatx4 a = {0.f,0.f,0.f,0.f};
#pragma unroll
          for (int ks = 0; ks < 4; ++ks) a = mfma(haf[ks], whf[g][ks], a);
          agh[g] = a;
        }
        u16* hw = pw ? hw1 : hw0;
#pragma unroll
        for (int r = 0; r < 4; ++r) {
          float s4 = s4cur[s][r];
          float tr = pipe[s][0][r] + __builtin_fmaf(s4, agh[0][r], bb0);
          float tz = pipe[s][1][r] + __builtin_fmaf(s4, agh[1][r], bb1);
          float xn_ = pipe[s][2][r] + bihv2;
          float hn_ = __builtin_fmaf(s4, agh[2][r], bhv2);
          float rg = frcp(1.f + __expf(-tr));
          float zg = frcp(1.f + __expf(-tz));
          float ni = __builtin_fmaf(rg, hn_, xn_);
          float ng = __builtin_fmaf(2.f, frcp(1.f + __expf(-2.f*ni)), -1.f);
          float hold = hreg[r] * s4;
          float hnew = __builtin_fmaf(zg, hold - ng, ng);
          hreg[r] = hnew;
          hw[r*8] = f2bf(hnew);
        }
      }
      if (s3on) {
        short8 h2a[4];
#pragma unroll
        for (int ks = 0; ks < 4; ++ks)
          h2a[ks] = *(const short8*)(&h2f[pw^1][0] + ks*512 + lane*8);
#pragma unroll
        for (int g = 0; g < 3; ++g) {
          floatx4 a = {0.f,0.f,0.f,0.f};
#pragma unroll
          for (int ks = 0; ks < 4; ++ks) a = mfma(h2a[ks], wif[g][ks], a);
          pipe[s][g] = a;
        }
      }
      barrier_lds();
    }
    if (ST || (t0 + 6 < TT)) {
      if constexpr (BF) {
#pragma unroll
        for (int ss = 0; ss < 2; ++ss) { xc[ss][0] = xn[ss][0]; xc[ss][1] = xn[ss][1]; }
      } else {
#pragma unroll
        for (int ss = 0; ss < 2; ++ss) {
          size_t base = ((size_t)(t0+6+ss)*BB + b0 + n16)*SS + q*8;
          xc[ss][0] = ld8<false>(x, base);
          xc[ss][1] = ld8<false>(x, base + 32);
        }
      }
    }
    if (ST || (t0+2 >= 0 && t0+2 < TT)) {
      if constexpr (BF) {
#pragma unroll
        for (int ss = 0; ss < 2; ++ss) {
          s4cur[ss][0] = 1.f - bf2f((u16)(draw[ss].x & 0xFFFF));
          s4cur[ss][1] = 1.f - bf2f((u16)(draw[ss].x >> 16));
          s4cur[ss][2] = 1.f - bf2f((u16)(draw[ss].y & 0xFFFF));
          s4cur[ss][3] = 1.f - bf2f((u16)(draw[ss].y >> 16));
        }
      } else {
#pragma unroll
        for (int ss = 0; ss < 2; ++ss)
#pragma unroll
          for (int r = 0; r < 4; ++r) s4cur[ss][r] = 1.f - fdraw[ss][r];
      }
    }
  };

  iter(-4, FalseT{});
  iter(-2, FalseT{});
  for (int t0 = 0; t0 <= TT - 8; t0 += 2) iter(t0, TrueT{});
  iter(TT-6, FalseT{});
  iter(TT-4, FalseT{});
  iter(TT-2, FalseT{});

  {
    if (wv == 1 || wv == 2) {
      short8 haf[4];
#pragma unroll
      for (int ks = 0; ks < 4; ++ks) haf[ks] = *(const short8*)(&hbuf[0][0] + ks*512 + lane*8);
      floatx4 a = {0.f,0.f,0.f,0.f};
#pragma unroll
      for (int ks = 0; ks < 4; ++ks) a = mfma(haf[ks], scf[ks], a);
      if (wv == 1) {
#pragma unroll
        for (int r = 0; r < 4; ++r)
          lgws[((size_t)(TT-1)*BB + b0 + 4*q + r)*16 + n16] = a[r] + bav;
      } else if (n16 == 0) {
#pragma unroll
        for (int r = 0; r < 4; ++r)
          vws[(size_t)(TT-1)*BB + b0 + 4*q + r] = a[r] + bcv;
      }
    }
#pragma unroll
    for (int r = 0; r < 4; ++r)
      st1<BF>(out, (size_t)3*TBR + (size_t)(b0 + 4*q + r)*HH + jj, hreg[r]);
  }
}

// ---------------------------------------------------------------------------
// K3: data-parallel head finisher (unchanged).
// ---------------------------------------------------------------------------
template<bool BF>
__global__ __launch_bounds__(256) void k_head(
    const float* __restrict__ lgws, const float* __restrict__ vws,
    const int* __restrict__ action, const void* __restrict__ W1,
    void* __restrict__ out)
{
  if (buf_is_bf16((const u16*)W1) != BF) return;
  size_t row = (size_t)blockIdx.x * 256 + threadIdx.x;
  if (row >= (size_t)TBR) return;
  const float* lp = lgws + row*16;
  floatx4 v[4];
#pragma unroll
  for (int i = 0; i < 4; ++i) v[i] = *(const floatx4*)(lp + 4*i);
  float mx = v[0][0];
#pragma unroll
  for (int i = 0; i < 4; ++i)
#pragma unroll
    for (int j = 0; j < 4; ++j) mx = fmaxf(mx, v[i][j]);
  float sum = 0.f, se = 0.f;
#pragma unroll
  for (int i = 0; i < 4; ++i)
#pragma unroll
    for (int j = 0; j < 4; ++j) {
      float d = v[i][j] - mx;
      float e = __expf(d);
      sum += e; se = __builtin_fmaf(e, d, se);
    }
  float ls = __logf(sum);
  int a = action[row];
  float la = lp[a];
  float lpa = (la - mx) - ls;
  float ent = ls - se * frcp(sum);
  st1<BF>(out, row*3,     lpa);
  st1<BF>(out, row*3 + 1, ent);
  st1<BF>(out, row*3 + 2, vws[row]);
}

// ---------------------------------------------------------------------------
extern "C" void kernel_launch(void* const* d_in, const int* in_sizes, int n_in,
                              void* d_out, int out_size, void* d_ws, size_t ws_size,
                              hipStream_t stream) {
  const void* x    = d_in[0];
  const void* done = d_in[1];
  const int*  act  = (const int*)d_in[2];
  const void* gst  = d_in[3];
  const void* W1   = d_in[4];
  const void* b1   = d_in[5];
  const void* W2   = d_in[6];
  const void* b2   = d_in[7];
  const void* Wih  = d_in[8];
  const void* bih  = d_in[9];
  const void* Whh  = d_in[10];
  const void* bhh  = d_in[11];
  const void* Wa   = d_in[12];
  const void* ba   = d_in[13];
  const void* Wc   = d_in[14];
  const void* bc   = d_in[15];

  float* lgws = (float*)d_ws;                       // [TBR,16] fp32 = 33.6 MB
  float* vws  = lgws + (size_t)16*TBR;              // [TBR]    fp32 =  2.1 MB
  const size_t h2g_off   = (size_t)(16*TBR + TBR)*4;
  const size_t flags_off = h2g_off + (size_t)NTILE*4096;     // h2g = 134 MB
  const size_t need_split = flags_off;
  const size_t need_fused = flags_off + (size_t)NTILE*4;     // +128 KB flags
  u16* h2g   = (u16*)((char*)d_ws + h2g_off);
  u32* flags = (u32*)((char*)d_ws + flags_off);

  if (ws_size >= need_fused) {
    hipMemsetAsync(flags, 0, (size_t)NTILE*4, stream);
    hipLaunchKernelGGL((k_fused<true>),  dim3(NPROD+NCONS), dim3(512), 0, stream,
                       x, done, gst, W1, b1, W2, b2, Wih, bih,
                       Whh, bhh, Wa, ba, Wc, bc, h2g, flags, lgws, vws, d_out);
    hipLaunchKernelGGL((k_fused<false>), dim3(NPROD+NCONS), dim3(512), 0, stream,
                       x, done, gst, W1, b1, W2, b2, Wih, bih,
                       Whh, bhh, Wa, ba, Wc, bc, h2g, flags, lgws, vws, d_out);
  } else if (ws_size >= need_split) {
    hipLaunchKernelGGL((k_mlp<true>),  dim3(NPROD), dim3(512), 0, stream,
                       x, W1, b1, W2, b2, h2g);
    hipLaunchKernelGGL((k_mlp<false>), dim3(NPROD), dim3(512), 0, stream,
                       x, W1, b1, W2, b2, h2g);
    hipLaunchKernelGGL((k_scan_split<true>),  dim3(NCONS), dim3(512), 0, stream,
                       done, gst, Wih, bih, Whh, bhh, Wa, ba, Wc, bc,
                       W1, h2g, lgws, vws, d_out);
    hipLaunchKernelGGL((k_scan_split<false>), dim3(NCONS), dim3(512), 0, stream,
                       done, gst, Wih, bih, Whh, bhh, Wa, ba, Wc, bc,
                       W1, h2g, lgws, vws, d_out);
  } else {
    hipLaunchKernelGGL((k_scan_mono<true>),  dim3(64), dim3(512), 0, stream,
                       x, done, gst, W1, b1, W2, b2, Wih, bih,
                       Whh, bhh, Wa, ba, Wc, bc, lgws, vws, d_out);
    hipLaunchKernelGGL((k_scan_mono<false>), dim3(64), dim3(512), 0, stream,
                       x, done, gst, W1, b1, W2, b2, Wih, bih,
                       Whh, bhh, Wa, ba, Wc, bc, lgws, vws, d_out);
  }
  hipLaunchKernelGGL((k_head<true>),  dim3(TBR/256), dim3(256), 0, stream,
                     lgws, vws, act, W1, d_out);
  hipLaunchKernelGGL((k_head<false>), dim3(TBR/256), dim3(256), 0, stream,
                     lgws, vws, act, W1, d_out);
}

// Round 5
// 815.861 us; speedup vs baseline: 2.9331x; 2.9331x over previous
//
#include <hip/hip_runtime.h>
#include <stdint.h>

// dims fixed by the reference
#define TT 512
#define BB 1024
#define SS 64
#define HH 128
#define TBR (TT*BB)
#define NTILE (TBR/16)     // 32768 16-row MFMA tiles, tile(t,bx) = t*64+bx
#define MTPB 16            // tiles per k_mlp block
#define MGRID (NTILE/MTPB) // 2048

typedef __attribute__((ext_vector_type(8))) short short8;    // 8 x bf16
typedef __attribute__((ext_vector_type(4))) float floatx4;   // MFMA acc
typedef unsigned short u16;
typedef unsigned int u32;
typedef struct { u32 x, y; } u32x2;

struct TrueT  { static constexpr bool value = true;  };
struct FalseT { static constexpr bool value = false; };

__device__ __forceinline__ float bf2f(u16 u){union{u32 i;float f;}v;v.i=((u32)u)<<16;return v.f;}
__device__ __forceinline__ u16 f2bf(float f){union{float f;u32 i;}v;v.f=f;u32 r=v.i+0x7FFFu+((v.i>>16)&1u);return (u16)(r>>16);}
__device__ __forceinline__ float frcp(float x){ return __builtin_amdgcn_rcpf(x); }

// Deterministic dtype detector (R3-proven).
__device__ __forceinline__ bool buf_is_bf16(const u16* p) {
  int ok = 0;
#pragma unroll
  for (int i = 0; i < 32; ++i) {
    u32 v = p[2*i] & 0x7FFFu;
    u32 e = v >> 7;
    ok += (v == 0u || (e >= 96u && e <= 128u)) ? 1 : 0;
  }
  return ok >= 24;
}

template<bool BF> __device__ __forceinline__ float ld1(const void* p, size_t i){
  if constexpr (BF) return bf2f(((const u16*)p)[i]);
  else              return ((const float*)p)[i];
}
__device__ __forceinline__ short8 pack8(floatx4 a, floatx4 b){
  short8 r;
  r[0]=(short)f2bf(a[0]); r[1]=(short)f2bf(a[1]); r[2]=(short)f2bf(a[2]); r[3]=(short)f2bf(a[3]);
  r[4]=(short)f2bf(b[0]); r[5]=(short)f2bf(b[1]); r[6]=(short)f2bf(b[2]); r[7]=(short)f2bf(b[3]);
  return r;
}
template<bool BF> __device__ __forceinline__ short8 ld8(const void* p, size_t i){
  if constexpr (BF) return *(const short8*)((const u16*)p + i);
  else {
    const float* f = (const float*)p + i;
    return pack8(*(const floatx4*)f, *(const floatx4*)(f + 4));
  }
}
template<bool BF> __device__ __forceinline__ void st1(void* p, size_t i, float v){
  if constexpr (BF) ((u16*)p)[i] = f2bf(v);
  else              ((float*)p)[i] = v;
}

// LDS-only barrier (R4-proven): lgkmcnt(0)+s_barrier, no vmcnt drain.
__device__ __forceinline__ void barrier_lds() {
  __asm__ __volatile__("" ::: "memory");
  __builtin_amdgcn_s_waitcnt(0xC07F);
  __builtin_amdgcn_s_barrier();
  __asm__ __volatile__("" ::: "memory");
}

// A-fragment-ordered LDS index for v_mfma_f32_16x16x32_bf16 (R3/R4-proven).
__device__ __forceinline__ int fragidx(int m,int k){
  return ((k>>5)<<9)+((m+(((k>>3)&3)<<4))<<3)+(k&7);
}
__device__ __forceinline__ floatx4 mfma(short8 a, short8 b, floatx4 c){
  return __builtin_amdgcn_mfma_f32_16x16x32_bf16(a,b,c,0,0,0);
}

// ---------------------------------------------------------------------------
// K1 (R9): batch MLP, R6's pipelined structure restored + residency fix.
// __launch_bounds__(512,4) => 2 blocks/CU resident (R6's (512,2) gave only
// 1 block/CU: w*4/(B/64) = 1 -- the main reason k_mlp was ~285us for ~45us
// of traffic). x prefetch deepened to 2 tiles (static slot indices via full
// unroll). 1 barrier per iteration, 3-stage pipeline S1(i)/S2(i-1)/DUMP(i-2).
// Output per 16-row tile in MFMA A-frag layout (4KB/tile).
// ---------------------------------------------------------------------------
template<bool BF>
__global__ __launch_bounds__(512, 4) void k_mlp(
    const void* __restrict__ x,
    const void* __restrict__ W1, const void* __restrict__ b1,
    const void* __restrict__ W2, const void* __restrict__ b2,
    u16* __restrict__ h2g)
{
  if (buf_is_bf16((const u16*)W1) != BF) return;
  const int tid = threadIdx.x, lane = tid & 63, wv = tid >> 6;
  const int n16 = lane & 15, q = lane >> 4;
  const int jj = 16*wv + n16;

  __shared__ __align__(16) u16 h1f[2][2048];
  __shared__ __align__(16) u16 h2f[2][2048];

  short8 w1f[2], w2f[4];
  float b1v, b2v;
#pragma unroll
  for (int ks = 0; ks < 2; ++ks) w1f[ks] = ld8<BF>(W1, (size_t)jj*SS + ks*32 + q*8);
  b1v = ld1<BF>(b1, jj);
#pragma unroll
  for (int ks = 0; ks < 4; ++ks) w2f[ks] = ld8<BF>(W2, (size_t)jj*HH + ks*32 + q*8);
  b2v = ld1<BF>(b2, jj);

  const int tile0 = blockIdx.x * MTPB;

  // 2-deep x prefetch (ping-pong slots; all indices static via full unroll)
  short8 xb[2][2]; floatx4 xf[2][4];
#pragma unroll
  for (int d = 0; d < 2; ++d) {
    size_t base = ((size_t)(tile0+d)*16 + n16)*SS + q*8;
    if constexpr (BF) {
      xb[d][0] = *(const short8*)((const u16*)x + base);
      xb[d][1] = *(const short8*)((const u16*)x + base + 32);
    } else {
      const float* f = (const float*)x + base;
      xf[d][0] = *(const floatx4*)f;       xf[d][1] = *(const floatx4*)(f+4);
      xf[d][2] = *(const floatx4*)(f+32);  xf[d][3] = *(const floatx4*)(f+36);
    }
  }

#pragma unroll
  for (int i = 0; i < MTPB + 2; ++i) {
    const int sl = i & 1;
    // S1: tile i -> h1f[i&1]
    if (i < MTPB) {
      short8 xc0, xc1;
      if constexpr (BF) { xc0 = xb[sl][0]; xc1 = xb[sl][1]; }
      else              { xc0 = pack8(xf[sl][0], xf[sl][1]); xc1 = pack8(xf[sl][2], xf[sl][3]); }
      // refill slot with tile i+2 (regs just consumed)
      if (i + 2 < MTPB) {
        size_t base = ((size_t)(tile0+i+2)*16 + n16)*SS + q*8;
        if constexpr (BF) {
          xb[sl][0] = *(const short8*)((const u16*)x + base);
          xb[sl][1] = *(const short8*)((const u16*)x + base + 32);
        } else {
          const float* f = (const float*)x + base;
          xf[sl][0] = *(const floatx4*)f;       xf[sl][1] = *(const floatx4*)(f+4);
          xf[sl][2] = *(const floatx4*)(f+32);  xf[sl][3] = *(const floatx4*)(f+36);
        }
      }
      floatx4 a = {0.f,0.f,0.f,0.f};
      a = mfma(xc0, w1f[0], a);
      a = mfma(xc1, w1f[1], a);
#pragma unroll
      for (int r = 0; r < 4; ++r) {
        float v = a[r] + b1v; v = v > 0.f ? v : 0.f;
        h1f[i&1][fragidx(4*q + r, jj)] = f2bf(v);
      }
    }
    // S2: tile i-1 (reads h1f[(i-1)&1] written last iter, pre-barrier-safe)
    if (i >= 1 && i <= MTPB) {
      short8 h1a[4];
#pragma unroll
      for (int ks = 0; ks < 4; ++ks)
        h1a[ks] = *(const short8*)(&h1f[(i-1)&1][0] + ks*512 + lane*8);
      floatx4 a = {0.f,0.f,0.f,0.f};
#pragma unroll
      for (int ks = 0; ks < 4; ++ks) a = mfma(h1a[ks], w2f[ks], a);
#pragma unroll
      for (int r = 0; r < 4; ++r) {
        float v = a[r] + b2v; v = v > 0.f ? v : 0.f;
        h2f[(i-1)&1][fragidx(4*q + r, jj)] = f2bf(v);
      }
    }
    // DUMP: tile i-2 frag -> global, coalesced 8B/thread
    if (i >= 2) {
      const int td = tile0 + i - 2;
      u32x2 v2 = *(const u32x2*)(&h2f[i&1][tid*4]);
      *(u32x2*)(h2g + (size_t)td*2048 + tid*4) = v2;
    }
    barrier_lds();
  }
}

// ---------------------------------------------------------------------------
// K2 (R6-proven, 501us): GRU scan, MLP removed. Per step: haf LDS reads,
// stage3 (Wih on h2 A-frag streamed from global, 2-step reg prefetch), rec,
// heads, ONE barrier.
// ---------------------------------------------------------------------------
template<bool BF>
__global__ __launch_bounds__(512, 2) void k_scan_split(
    const void* __restrict__ done_, const void* __restrict__ gstate,
    const void* __restrict__ Wih, const void* __restrict__ bih,
    const void* __restrict__ Whh, const void* __restrict__ bhh,
    const void* __restrict__ Wa, const void* __restrict__ ba,
    const void* __restrict__ Wc, const void* __restrict__ bc,
    const void* __restrict__ W1,                   // dtype detector only
    const u16* __restrict__ h2g,
    float* __restrict__ lgws, float* __restrict__ vws,
    void* __restrict__ out)
{
  if (buf_is_bf16((const u16*)W1) != BF) return;

  const int tid = threadIdx.x, lane = tid & 63, wv = tid >> 6;
  const int n16 = lane & 15, q = lane >> 4;
  const int b0 = blockIdx.x * 16, bx = blockIdx.x;
  const int jj = 16*wv + n16;

  __shared__ __align__(16) u16 hbuf[2][2048];   // double-buffered h A-frag

  // ---- weights -> register B-fragments ---------------------------------
  short8 wif[3][4], whf[3][4], scf[4];
  float bihv2, bhv2, bb0, bb1;
  {
    float bi0, bi1, bh0, bh1;
#pragma unroll
    for (int g = 0; g < 3; ++g) {
      int grow = g*128 + jj;
#pragma unroll
      for (int ks = 0; ks < 4; ++ks) {
        wif[g][ks] = ld8<BF>(Wih, (size_t)grow*HH + ks*32 + q*8);
        whf[g][ks] = ld8<BF>(Whh, (size_t)grow*HH + ks*32 + q*8);
      }
      float bi = ld1<BF>(bih, grow), bh = ld1<BF>(bhh, grow);
      if (g == 0) { bi0 = bi; bh0 = bh; }
      else if (g == 1) { bi1 = bi; bh1 = bh; }
      else { bihv2 = bi; bhv2 = bh; }
    }
    bb0 = bi0 + bh0;
    bb1 = bi1 + bh1;
  }
  if (wv == 1) {
#pragma unroll
    for (int ks = 0; ks < 4; ++ks) scf[ks] = ld8<BF>(Wa, (size_t)n16*HH + ks*32 + q*8);
  } else if (wv == 2) {
#pragma unroll
    for (int ks = 0; ks < 4; ++ks) {
      short8 z = {0,0,0,0,0,0,0,0};
      if (n16 == 0) z = ld8<BF>(Wc, (size_t)ks*32 + q*8);
      scf[ks] = z;
    }
  } else {
#pragma unroll
    for (int ks = 0; ks < 4; ++ks) { short8 z = {0,0,0,0,0,0,0,0}; scf[ks] = z; }
  }
  const float bav = ld1<BF>(ba, n16);
  const float bcv = ld1<BF>(bc, 0);

  // ---- h0 state --------------------------------------------------------
  float hreg[4];
#pragma unroll
  for (int r = 0; r < 4; ++r) {
    hreg[r] = ld1<BF>(gstate, (size_t)(b0 + 4*q + r)*HH + jj);
    hbuf[0][fragidx(4*q + r, jj)] = f2bf(hreg[r]);
  }
  float s4cur[2][4];
#pragma unroll
  for (int s = 0; s < 2; ++s)
#pragma unroll
    for (int r = 0; r < 4; ++r)
      s4cur[s][r] = 1.f - ld1<BF>(done_, (size_t)s*BB + b0 + 4*q + r);
  u32x2 draw[2];  floatx4 fdraw[2];
#pragma unroll
  for (int s = 0; s < 2; ++s) { draw[s].x = draw[s].y = 0; fdraw[s] = floatx4{0,0,0,0}; }

  // ---- h2 frag prefetch (2-deep register double buffer) ----------------
  const u16* const hz = h2g + (size_t)bx*2048;      // tile(t) = t*64 + bx
  short8 h2p[2][4];
#pragma unroll
  for (int ks = 0; ks < 4; ++ks)
    h2p[0][ks] = *(const short8*)(hz + (size_t)0*64*2048 + ks*512 + lane*8);
#pragma unroll
  for (int ks = 0; ks < 4; ++ks)
    h2p[1][ks] = *(const short8*)(hz + (size_t)1*64*2048 + ks*512 + lane*8);
  floatx4 pipe[3];
#pragma unroll
  for (int g = 0; g < 3; ++g) {            // stage3(tile 0) -> pipe for rec(0)
    floatx4 a = {0.f,0.f,0.f,0.f};
#pragma unroll
    for (int ks = 0; ks < 4; ++ks) a = mfma(h2p[0][ks], wif[g][ks], a);
    pipe[g] = a;
  }
#pragma unroll
  for (int ks = 0; ks < 4; ++ks)           // tile 2 into buffer 0
    h2p[0][ks] = *(const short8*)(hz + (size_t)2*64*2048 + ks*512 + lane*8);
  __syncthreads();

  u16* hw0 = &hbuf[1][0] + fragidx(4*q, jj);   // even step writes hbuf[1]
  u16* hw1 = &hbuf[0][0] + fragidx(4*q, jj);   // odd  step writes hbuf[0]

  for (int t0 = 0; t0 < TT; t0 += 2) {
#pragma unroll
    for (int s = 0; s < 2; ++s) {
      const int t = t0 + s;
      const int pw = s;                    // t0 even => t&1 == s (static!)
      const int pb = s ^ 1;                // (t+1)&1 -- h2p buffer parity

      // 1) critical h reads first
      short8 haf[4];
#pragma unroll
      for (int ks = 0; ks < 4; ++ks)
        haf[ks] = *(const short8*)(&hbuf[pw][0] + ks*512 + lane*8);

      // 2) stage3: gx(tile t+1) from h2p[pb] (fills haf read latency)
      floatx4 pn[3];
#pragma unroll
      for (int g = 0; g < 3; ++g) {
        floatx4 a = {0.f,0.f,0.f,0.f};
#pragma unroll
        for (int ks = 0; ks < 4; ++ks) a = mfma(h2p[pb][ks], wif[g][ks], a);
        pn[g] = a;
      }
      // 3) refill: tile t+3 (clamped; redundant at tail, never consumed)
      {
        const int tl = (t+3 < TT) ? t+3 : TT-1;
        const u16* tp = hz + (size_t)tl*64*2048;
#pragma unroll
        for (int ks = 0; ks < 4; ++ks)
          h2p[pb][ks] = *(const short8*)(tp + ks*512 + lane*8);
      }

      // 4) head for t-1 (fire-and-forget)
      if (t > 0 && (wv == 1 || wv == 2)) {
        floatx4 a = {0.f,0.f,0.f,0.f};
#pragma unroll
        for (int ks = 0; ks < 4; ++ks) a = mfma(haf[ks], scf[ks], a);
        if (wv == 1) {
#pragma unroll
          for (int r = 0; r < 4; ++r)
            lgws[((size_t)(t-1)*BB + b0 + 4*q + r)*16 + n16] = a[r] + bav;
        } else if (n16 == 0) {
#pragma unroll
          for (int r = 0; r < 4; ++r)
            vws[(size_t)(t-1)*BB + b0 + 4*q + r] = a[r] + bcv;
        }
      }

      // 5) recurrence step t
      floatx4 agh[3];
#pragma unroll
      for (int g = 0; g < 3; ++g) {
        floatx4 a = {0.f,0.f,0.f,0.f};
#pragma unroll
        for (int ks = 0; ks < 4; ++ks) a = mfma(haf[ks], whf[g][ks], a);
        agh[g] = a;
      }
      u16* hw = pw ? hw1 : hw0;
#pragma unroll
      for (int r = 0; r < 4; ++r) {
        float s4 = s4cur[s][r];
        float tr = pipe[0][r] + __builtin_fmaf(s4, agh[0][r], bb0);
        float tz = pipe[1][r] + __builtin_fmaf(s4, agh[1][r], bb1);
        float xn_ = pipe[2][r] + bihv2;
        float hn_ = __builtin_fmaf(s4, agh[2][r], bhv2);
        float rg = frcp(1.f + __expf(-tr));
        float zg = frcp(1.f + __expf(-tz));
        float ni = __builtin_fmaf(rg, hn_, xn_);
        float ng = __builtin_fmaf(2.f, frcp(1.f + __expf(-2.f*ni)), -1.f);  // tanh
        float hold = hreg[r] * s4;
        float hnew = __builtin_fmaf(zg, hold - ng, ng);
        hreg[r] = hnew;
        hw[r*8] = f2bf(hnew);
      }

      // 6) done prefetch (per 2 steps; clamped at tail)
      if (s == 0) {
#pragma unroll
        for (int ss = 0; ss < 2; ++ss) {
          const int tl = (t0+2+ss < TT) ? t0+2+ss : TT-1;
          size_t didx = (size_t)tl*BB + b0 + 4*q;
          if constexpr (BF) draw[ss] = *(const u32x2*)((const u16*)done_ + didx);
          else              fdraw[ss] = *(const floatx4*)((const float*)done_ + didx);
        }
      }

      barrier_lds();                        // the ONE barrier per step
      // 7) rotate gx pipe
#pragma unroll
      for (int g = 0; g < 3; ++g) pipe[g] = pn[g];
    }
    // rotate done regs (tail values unused)
    if constexpr (BF) {
#pragma unroll
      for (int ss = 0; ss < 2; ++ss) {
        s4cur[ss][0] = 1.f - bf2f((u16)(draw[ss].x & 0xFFFF));
        s4cur[ss][1] = 1.f - bf2f((u16)(draw[ss].x >> 16));
        s4cur[ss][2] = 1.f - bf2f((u16)(draw[ss].y & 0xFFFF));
        s4cur[ss][3] = 1.f - bf2f((u16)(draw[ss].y >> 16));
      }
    } else {
#pragma unroll
      for (int ss = 0; ss < 2; ++ss)
#pragma unroll
        for (int r = 0; r < 4; ++r) s4cur[ss][r] = 1.f - fdraw[ss][r];
    }
  }

  // epilogue: head for t=511 (h_511 in hbuf[0]) + h_last output
  {
    if (wv == 1 || wv == 2) {
      short8 haf[4];
#pragma unroll
      for (int ks = 0; ks < 4; ++ks) haf[ks] = *(const short8*)(&hbuf[0][0] + ks*512 + lane*8);
      floatx4 a = {0.f,0.f,0.f,0.f};
#pragma unroll
      for (int ks = 0; ks < 4; ++ks) a = mfma(haf[ks], scf[ks], a);
      if (wv == 1) {
#pragma unroll
        for (int r = 0; r < 4; ++r)
          lgws[((size_t)(TT-1)*BB + b0 + 4*q + r)*16 + n16] = a[r] + bav;
      } else if (n16 == 0) {
#pragma unroll
        for (int r = 0; r < 4; ++r)
          vws[(size_t)(TT-1)*BB + b0 + 4*q + r] = a[r] + bcv;
      }
    }
#pragma unroll
    for (int r = 0; r < 4; ++r)
      st1<BF>(out, (size_t)3*TBR + (size_t)(b0 + 4*q + r)*HH + jj, hreg[r]);
  }
}

// ---------------------------------------------------------------------------
// Deep fallback (R5 mono) if workspace can't hold h2g.
// ---------------------------------------------------------------------------
template<bool BF>
__global__ __launch_bounds__(512, 2) void k_scan_mono(
    const void* __restrict__ x, const void* __restrict__ done_,
    const void* __restrict__ gstate,
    const void* __restrict__ W1, const void* __restrict__ b1,
    const void* __restrict__ W2, const void* __restrict__ b2,
    const void* __restrict__ Wih, const void* __restrict__ bih,
    const void* __restrict__ Whh, const void* __restrict__ bhh,
    const void* __restrict__ Wa, const void* __restrict__ ba,
    const void* __restrict__ Wc, const void* __restrict__ bc,
    float* __restrict__ lgws, float* __restrict__ vws,
    void* __restrict__ out)
{
  if (buf_is_bf16((const u16*)W1) != BF) return;

  const int tid = threadIdx.x, lane = tid & 63, wv = tid >> 6;
  const int n16 = lane & 15, q = lane >> 4;
  const int b0 = blockIdx.x * 16;
  const int jj = 16*wv + n16;

  __shared__ __align__(16) u16 hbuf[2][2048];
  __shared__ __align__(16) u16 h1f[2][2048];
  __shared__ __align__(16) u16 h2f[2][2048];

  short8 w1f[2], w2f[4], wif[3][4], whf[3][4], scf[4];
  float b1v, b2v, bihv2, bhv2, bb0, bb1;
  {
    int row = wv*16 + n16;
#pragma unroll
    for (int ks = 0; ks < 2; ++ks) w1f[ks] = ld8<BF>(W1, (size_t)row*SS + ks*32 + q*8);
    b1v = ld1<BF>(b1, row);
#pragma unroll
    for (int ks = 0; ks < 4; ++ks) w2f[ks] = ld8<BF>(W2, (size_t)row*HH + ks*32 + q*8);
    b2v = ld1<BF>(b2, row);
    float bi0, bi1, bh0, bh1;
#pragma unroll
    for (int g = 0; g < 3; ++g) {
      int grow = g*128 + jj;
#pragma unroll
      for (int ks = 0; ks < 4; ++ks) {
        wif[g][ks] = ld8<BF>(Wih, (size_t)grow*HH + ks*32 + q*8);
        whf[g][ks] = ld8<BF>(Whh, (size_t)grow*HH + ks*32 + q*8);
      }
      float bi = ld1<BF>(bih, grow), bh = ld1<BF>(bhh, grow);
      if (g == 0) { bi0 = bi; bh0 = bh; }
      else if (g == 1) { bi1 = bi; bh1 = bh; }
      else { bihv2 = bi; bhv2 = bh; }
    }
    bb0 = bi0 + bh0;
    bb1 = bi1 + bh1;
  }
  if (wv == 1) {
#pragma unroll
    for (int ks = 0; ks < 4; ++ks) scf[ks] = ld8<BF>(Wa, (size_t)n16*HH + ks*32 + q*8);
  } else if (wv == 2) {
#pragma unroll
    for (int ks = 0; ks < 4; ++ks) {
      short8 z = {0,0,0,0,0,0,0,0};
      if (n16 == 0) z = ld8<BF>(Wc, (size_t)ks*32 + q*8);
      scf[ks] = z;
    }
  } else {
#pragma unroll
    for (int ks = 0; ks < 4; ++ks) { short8 z = {0,0,0,0,0,0,0,0}; scf[ks] = z; }
  }
  const float bav = ld1<BF>(ba, n16);
  const float bcv = ld1<BF>(bc, 0);

  float hreg[4];
#pragma unroll
  for (int r = 0; r < 4; ++r) {
    hreg[r] = ld1<BF>(gstate, (size_t)(b0 + 4*q + r)*HH + jj);
    hbuf[0][fragidx(4*q + r, jj)] = f2bf(hreg[r]);
  }
  short8 xc[2][2], xn[2][2];
#pragma unroll
  for (int s = 0; s < 2; ++s)
#pragma unroll
    for (int ks = 0; ks < 2; ++ks)
      xc[s][ks] = ld8<BF>(x, ((size_t)s*BB + b0 + n16)*SS + ks*32 + q*8);
  float s4cur[2][4];
#pragma unroll
  for (int s = 0; s < 2; ++s)
#pragma unroll
    for (int r = 0; r < 4; ++r) s4cur[s][r] = 1.f;
  u32x2 draw[2];  floatx4 fdraw[2];
#pragma unroll
  for (int s = 0; s < 2; ++s) { draw[s].x = draw[s].y = 0; fdraw[s] = floatx4{0,0,0,0}; }
#pragma unroll
  for (int s = 0; s < 2; ++s)
#pragma unroll
    for (int ks = 0; ks < 2; ++ks) { short8 z={0,0,0,0,0,0,0,0}; xn[s][ks]=z; }
  floatx4 pipe[2][3];
#pragma unroll
  for (int s = 0; s < 2; ++s)
#pragma unroll
    for (int g = 0; g < 3; ++g) pipe[s][g] = floatx4{0.f,0.f,0.f,0.f};
  __syncthreads();

  u16* hw0 = &hbuf[1][0] + fragidx(4*q, jj);
  u16* hw1 = &hbuf[0][0] + fragidx(4*q, jj);

  auto iter = [&](int t0, auto steady) {
    constexpr bool ST = decltype(steady)::value;
#pragma unroll
    for (int s = 0; s < 2; ++s) {
      const int t = t0 + s;
      const bool s1on = ST || (t <= TT-5);
      const bool s2on = ST || (t >= -3 && t <= TT-4);
      const bool s3on = ST || (t >= -2 && t <= TT-3);
      const bool ron  = ST || (t >= 0);
      const int pw = t & 1;

      short8 haf[4];
      if (ron) {
#pragma unroll
        for (int ks = 0; ks < 4; ++ks)
          haf[ks] = *(const short8*)(&hbuf[pw][0] + ks*512 + lane*8);
      }
      if (s1on) {
        floatx4 a = {0.f,0.f,0.f,0.f};
        a = mfma(xc[s][0], w1f[0], a);
        a = mfma(xc[s][1], w1f[1], a);
#pragma unroll
        for (int r = 0; r < 4; ++r) {
          float v = a[r] + b1v; v = v > 0.f ? v : 0.f;
          h1f[pw][fragidx(4*q + r, jj)] = f2bf(v);
        }
      }
      if (s2on) {
        short8 h1a[4];
#pragma unroll
        for (int ks = 0; ks < 4; ++ks)
          h1a[ks] = *(const short8*)(&h1f[pw^1][0] + ks*512 + lane*8);
        floatx4 a = {0.f,0.f,0.f,0.f};
#pragma unroll
        for (int ks = 0; ks < 4; ++ks) a = mfma(h1a[ks], w2f[ks], a);
#pragma unroll
        for (int r = 0; r < 4; ++r) {
          float v = a[r] + b2v; v = v > 0.f ? v : 0.f;
          h2f[pw][fragidx(4*q + r, jj)] = f2bf(v);
        }
      }
      if (s == 0) {
        if (ST || (t0 + 6 < TT)) {
          if constexpr (BF) {
#pragma unroll
            for (int ss = 0; ss < 2; ++ss) {
              size_t base = ((size_t)(t0+6+ss)*BB + b0 + n16)*SS + q*8;
              xn[ss][0] = *(const short8*)((const u16*)x + base);
              xn[ss][1] = *(const short8*)((const u16*)x + base + 32);
            }
          }
        }
        if (ST || (t0+2 >= 0 && t0+2 < TT)) {
#pragma unroll
          for (int ss = 0; ss < 2; ++ss) {
            size_t didx = (size_t)(t0+2+ss)*BB + b0 + 4*q;
            if constexpr (BF) draw[ss] = *(const u32x2*)((const u16*)done_ + didx);
            else              fdraw[ss] = *(const floatx4*)((const float*)done_ + didx);
          }
        }
      }
      if (ron) {
        if (t > 0 && (wv == 1 || wv == 2)) {
          floatx4 a = {0.f,0.f,0.f,0.f};
#pragma unroll
          for (int ks = 0; ks < 4; ++ks) a = mfma(haf[ks], scf[ks], a);
          if (wv == 1) {
#pragma unroll
            for (int r = 0; r < 4; ++r)
              lgws[((size_t)(t-1)*BB + b0 + 4*q + r)*16 + n16] = a[r] + bav;
          } else if (n16 == 0) {
#pragma unroll
            for (int r = 0; r < 4; ++r)
              vws[(size_t)(t-1)*BB + b0 + 4*q + r] = a[r] + bcv;
          }
        }
        floatx4 agh[3];
#pragma unroll
        for (int g = 0; g < 3; ++g) {
          floatx4 a = {0.f,0.f,0.f,0.f};
#pragma unroll
          for (int ks = 0; ks < 4; ++ks) a = mfma(haf[ks], whf[g][ks], a);
          agh[g] = a;
        }
        u16* hw = pw ? hw1 : hw0;
#pragma unroll
        for (int r = 0; r < 4; ++r) {
          float s4 = s4cur[s][r];
          float tr = pipe[s][0][r] + __builtin_fmaf(s4, agh[0][r], bb0);
          float tz = pipe[s][1][r] + __builtin_fmaf(s4, agh[1][r], bb1);
          float xn_ = pipe[s][2][r] + bihv2;
          float hn_ = __builtin_fmaf(s4, agh[2][r], bhv2);
          float rg = frcp(1.f + __expf(-tr));
          float zg = frcp(1.f + __expf(-tz));
          float ni = __builtin_fmaf(rg, hn_, xn_);
          float ng = __builtin_fmaf(2.f, frcp(1.f + __expf(-2.f*ni)), -1.f);
          float hold = hreg[r] * s4;
          float hnew = __builtin_fmaf(zg, hold - ng, ng);
          hreg[r] = hnew;
          hw[r*8] = f2bf(hnew);
        }
      }
      if (s3on) {
        short8 h2a[4];
#pragma unroll
        for (int ks = 0; ks < 4; ++ks)
          h2a[ks] = *(const short8*)(&h2f[pw^1][0] + ks*512 + lane*8);
#pragma unroll
        for (int g = 0; g < 3; ++g) {
          floatx4 a = {0.f,0.f,0.f,0.f};
#pragma unroll
          for (int ks = 0; ks < 4; ++ks) a = mfma(h2a[ks], wif[g][ks], a);
          pipe[s][g] = a;
        }
      }
      barrier_lds();
    }
    if (ST || (t0 + 6 < TT)) {
      if constexpr (BF) {
#pragma unroll
        for (int ss = 0; ss < 2; ++ss) { xc[ss][0] = xn[ss][0]; xc[ss][1] = xn[ss][1]; }
      } else {
#pragma unroll
        for (int ss = 0; ss < 2; ++ss) {
          size_t base = ((size_t)(t0+6+ss)*BB + b0 + n16)*SS + q*8;
          xc[ss][0] = ld8<false>(x, base);
          xc[ss][1] = ld8<false>(x, base + 32);
        }
      }
    }
    if (ST || (t0+2 >= 0 && t0+2 < TT)) {
      if constexpr (BF) {
#pragma unroll
        for (int ss = 0; ss < 2; ++ss) {
          s4cur[ss][0] = 1.f - bf2f((u16)(draw[ss].x & 0xFFFF));
          s4cur[ss][1] = 1.f - bf2f((u16)(draw[ss].x >> 16));
          s4cur[ss][2] = 1.f - bf2f((u16)(draw[ss].y & 0xFFFF));
          s4cur[ss][3] = 1.f - bf2f((u16)(draw[ss].y >> 16));
        }
      } else {
#pragma unroll
        for (int ss = 0; ss < 2; ++ss)
#pragma unroll
          for (int r = 0; r < 4; ++r) s4cur[ss][r] = 1.f - fdraw[ss][r];
      }
    }
  };

  iter(-4, FalseT{});
  iter(-2, FalseT{});
  for (int t0 = 0; t0 <= TT - 8; t0 += 2) iter(t0, TrueT{});
  iter(TT-6, FalseT{});
  iter(TT-4, FalseT{});
  iter(TT-2, FalseT{});

  {
    if (wv == 1 || wv == 2) {
      short8 haf[4];
#pragma unroll
      for (int ks = 0; ks < 4; ++ks) haf[ks] = *(const short8*)(&hbuf[0][0] + ks*512 + lane*8);
      floatx4 a = {0.f,0.f,0.f,0.f};
#pragma unroll
      for (int ks = 0; ks < 4; ++ks) a = mfma(haf[ks], scf[ks], a);
      if (wv == 1) {
#pragma unroll
        for (int r = 0; r < 4; ++r)
          lgws[((size_t)(TT-1)*BB + b0 + 4*q + r)*16 + n16] = a[r] + bav;
      } else if (n16 == 0) {
#pragma unroll
        for (int r = 0; r < 4; ++r)
          vws[(size_t)(TT-1)*BB + b0 + 4*q + r] = a[r] + bcv;
      }
    }
#pragma unroll
    for (int r = 0; r < 4; ++r)
      st1<BF>(out, (size_t)3*TBR + (size_t)(b0 + 4*q + r)*HH + jj, hreg[r]);
  }
}

// ---------------------------------------------------------------------------
// K3: data-parallel head finisher (unchanged).
// ---------------------------------------------------------------------------
template<bool BF>
__global__ __launch_bounds__(256) void k_head(
    const float* __restrict__ lgws, const float* __restrict__ vws,
    const int* __restrict__ action, const void* __restrict__ W1,
    void* __restrict__ out)
{
  if (buf_is_bf16((const u16*)W1) != BF) return;
  size_t row = (size_t)blockIdx.x * 256 + threadIdx.x;
  if (row >= (size_t)TBR) return;
  const float* lp = lgws + row*16;
  floatx4 v[4];
#pragma unroll
  for (int i = 0; i < 4; ++i) v[i] = *(const floatx4*)(lp + 4*i);
  float mx = v[0][0];
#pragma unroll
  for (int i = 0; i < 4; ++i)
#pragma unroll
    for (int j = 0; j < 4; ++j) mx = fmaxf(mx, v[i][j]);
  float sum = 0.f, se = 0.f;
#pragma unroll
  for (int i = 0; i < 4; ++i)
#pragma unroll
    for (int j = 0; j < 4; ++j) {
      float d = v[i][j] - mx;
      float e = __expf(d);
      sum += e; se = __builtin_fmaf(e, d, se);
    }
  float ls = __logf(sum);
  int a = action[row];
  float la = lp[a];
  float lpa = (la - mx) - ls;
  float ent = ls - se * frcp(sum);
  st1<BF>(out, row*3,     lpa);
  st1<BF>(out, row*3 + 1, ent);
  st1<BF>(out, row*3 + 2, vws[row]);
}

// ---------------------------------------------------------------------------
extern "C" void kernel_launch(void* const* d_in, const int* in_sizes, int n_in,
                              void* d_out, int out_size, void* d_ws, size_t ws_size,
                              hipStream_t stream) {
  const void* x    = d_in[0];
  const void* done = d_in[1];
  const int*  act  = (const int*)d_in[2];
  const void* gst  = d_in[3];
  const void* W1   = d_in[4];
  const void* b1   = d_in[5];
  const void* W2   = d_in[6];
  const void* b2   = d_in[7];
  const void* Wih  = d_in[8];
  const void* bih  = d_in[9];
  const void* Whh  = d_in[10];
  const void* bhh  = d_in[11];
  const void* Wa   = d_in[12];
  const void* ba   = d_in[13];
  const void* Wc   = d_in[14];
  const void* bc   = d_in[15];

  float* lgws = (float*)d_ws;                       // [TBR,16] fp32 = 33.6 MB
  float* vws  = lgws + (size_t)16*TBR;              // [TBR]    fp32 =  2.1 MB
  u16*   h2g  = (u16*)(vws + (size_t)TBR);          // [NTILE,2048] bf16 frag = 134 MB
  const size_t need = (size_t)(16*TBR + TBR)*4 + (size_t)NTILE*4096;

  if (ws_size >= need) {
    hipLaunchKernelGGL((k_mlp<true>),  dim3(MGRID), dim3(512), 0, stream,
                       x, W1, b1, W2, b2, h2g);
    hipLaunchKernelGGL((k_mlp<false>), dim3(MGRID), dim3(512), 0, stream,
                       x, W1, b1, W2, b2, h2g);
    hipLaunchKernelGGL((k_scan_split<true>),  dim3(64), dim3(512), 0, stream,
                       done, gst, Wih, bih, Whh, bhh, Wa, ba, Wc, bc,
                       W1, h2g, lgws, vws, d_out);
    hipLaunchKernelGGL((k_scan_split<false>), dim3(64), dim3(512), 0, stream,
                       done, gst, Wih, bih, Whh, bhh, Wa, ba, Wc, bc,
                       W1, h2g, lgws, vws, d_out);
  } else {
    hipLaunchKernelGGL((k_scan_mono<true>),  dim3(64), dim3(512), 0, stream,
                       x, done, gst, W1, b1, W2, b2, Wih, bih,
                       Whh, bhh, Wa, ba, Wc, bc, lgws, vws, d_out);
    hipLaunchKernelGGL((k_scan_mono<false>), dim3(64), dim3(512), 0, stream,
                       x, done, gst, W1, b1, W2, b2, Wih, bih,
                       Whh, bhh, Wa, ba, Wc, bc, lgws, vws, d_out);
  }
  hipLaunchKernelGGL((k_head<true>),  dim3(TBR/256), dim3(256), 0, stream,
                     lgws, vws, act, W1, d_out);
  hipLaunchKernelGGL((k_head<false>), dim3(TBR/256), dim3(256), 0, stream,
                     lgws, vws, act, W1, d_out);
}

// Round 7
// 758.883 us; speedup vs baseline: 3.1534x; 1.0751x over previous
//
#include <hip/hip_runtime.h>
#include <stdint.h>

// dims fixed by the reference
#define TT 512
#define BB 1024
#define SS 64
#define HH 128
#define TBR (TT*BB)
#define NTILE (TBR/16)     // 32768 16-row MFMA tiles, tile(t,bx) = t*64+bx
#define MW_TPW 16          // tiles per wave in k_mlp
#define MGRID (NTILE/(4*MW_TPW))   // 512 blocks x 4 waves

typedef __attribute__((ext_vector_type(8))) short short8;    // 8 x bf16
typedef __attribute__((ext_vector_type(4))) float floatx4;   // MFMA acc
typedef unsigned short u16;
typedef unsigned int u32;
typedef struct { u32 x, y; } u32x2;

struct TrueT  { static constexpr bool value = true;  };
struct FalseT { static constexpr bool value = false; };

__device__ __forceinline__ float bf2f(u16 u){union{u32 i;float f;}v;v.i=((u32)u)<<16;return v.f;}
__device__ __forceinline__ u16 f2bf(float f){union{float f;u32 i;}v;v.f=f;u32 r=v.i+0x7FFFu+((v.i>>16)&1u);return (u16)(r>>16);}
__device__ __forceinline__ float frcp(float x){ return __builtin_amdgcn_rcpf(x); }

// Deterministic dtype detector (R3-proven).
__device__ __forceinline__ bool buf_is_bf16(const u16* p) {
  int ok = 0;
#pragma unroll
  for (int i = 0; i < 32; ++i) {
    u32 v = p[2*i] & 0x7FFFu;
    u32 e = v >> 7;
    ok += (v == 0u || (e >= 96u && e <= 128u)) ? 1 : 0;
  }
  return ok >= 24;
}

template<bool BF> __device__ __forceinline__ float ld1(const void* p, size_t i){
  if constexpr (BF) return bf2f(((const u16*)p)[i]);
  else              return ((const float*)p)[i];
}
__device__ __forceinline__ short8 pack8(floatx4 a, floatx4 b){
  short8 r;
  r[0]=(short)f2bf(a[0]); r[1]=(short)f2bf(a[1]); r[2]=(short)f2bf(a[2]); r[3]=(short)f2bf(a[3]);
  r[4]=(short)f2bf(b[0]); r[5]=(short)f2bf(b[1]); r[6]=(short)f2bf(b[2]); r[7]=(short)f2bf(b[3]);
  return r;
}
template<bool BF> __device__ __forceinline__ short8 ld8(const void* p, size_t i){
  if constexpr (BF) return *(const short8*)((const u16*)p + i);
  else {
    const float* f = (const float*)p + i;
    return pack8(*(const floatx4*)f, *(const floatx4*)(f + 4));
  }
}
template<bool BF> __device__ __forceinline__ void st1(void* p, size_t i, float v){
  if constexpr (BF) ((u16*)p)[i] = f2bf(v);
  else              ((float*)p)[i] = v;
}

// LDS-only barrier (R4-proven): lgkmcnt(0)+s_barrier, no vmcnt drain.
__device__ __forceinline__ void barrier_lds() {
  __asm__ __volatile__("" ::: "memory");
  __builtin_amdgcn_s_waitcnt(0xC07F);
  __builtin_amdgcn_s_barrier();
  __asm__ __volatile__("" ::: "memory");
}

// A-fragment-ordered LDS index for v_mfma_f32_16x16x32_bf16 (R3/R4-proven).
__device__ __forceinline__ int fragidx(int m,int k){
  return ((k>>5)<<9)+((m+(((k>>3)&3)<<4))<<3)+(k&7);
}
__device__ __forceinline__ floatx4 mfma(short8 a, short8 b, floatx4 c){
  return __builtin_amdgcn_mfma_f32_16x16x32_bf16(a,b,c,0,0,0);
}

// ---------------------------------------------------------------------------
// K1 (R10/R11 resubmit): batch MLP, BARRIER-FREE per-wave tiles. Each wave
// computes whole 16x128 tiles alone: W1 B-frags in regs, W2 B-frags from a
// per-block LDS table (filled once, one barrier), per-wave 4KB LDS scratch
// for the C-frag->A-frag transposes (same-wave RAW: lgkmcnt only, NO
// barriers in the tile loop). 512 blocks x 4 waves x 16 tiles = NTILE; all
// blocks resident in one round. Identical op order / rounding to the
// block-wide version.
// ---------------------------------------------------------------------------
template<bool BF>
__global__ __launch_bounds__(256, 2) void k_mlp(
    const void* __restrict__ x,
    const void* __restrict__ W1, const void* __restrict__ b1,
    const void* __restrict__ W2, const void* __restrict__ b2,
    u16* __restrict__ h2g)
{
  if (buf_is_bf16((const u16*)W1) != BF) return;
  const int tid = threadIdx.x, lane = tid & 63, wv = tid >> 6;   // wv 0..3
  const int n16 = lane & 15, q = lane >> 4;

  __shared__ __align__(16) u16 W2L[8*4*64*8];   // 32 KB B-frag table
  __shared__ __align__(16) u16 scr[4][2048];    // 4 KB per-wave scratch

  // ---- fill W2 B-frag table (once per block) --------------------------
  for (int s = tid; s < 2048; s += 256) {
    int j = s >> 8, ks = (s >> 6) & 3, l = s & 63;
    short8 v = ld8<BF>(W2, (size_t)(16*j + (l & 15))*HH + ks*32 + (l >> 4)*8);
    *(short8*)&W2L[(size_t)s*8] = v;
  }
  // ---- W1 B-frags + biases -> regs ------------------------------------
  short8 w1b[8][2]; float b1v[8], b2v[8];
#pragma unroll
  for (int j = 0; j < 8; ++j) {
    int row = 16*j + n16;
#pragma unroll
    for (int ks = 0; ks < 2; ++ks) w1b[j][ks] = ld8<BF>(W1, (size_t)row*SS + ks*32 + q*8);
    b1v[j] = ld1<BF>(b1, row);
    b2v[j] = ld1<BF>(b2, row);
  }
  __syncthreads();                               // W2L ready (the ONLY barrier)

  u16* S = scr[wv];
  const int tile0 = (blockIdx.x * 4 + wv) * MW_TPW;

  // 1-deep x prefetch (named regs only -- no runtime-indexed arrays)
  short8 xb0, xb1; floatx4 xf0, xf1, xf2, xf3;
  {
    size_t base = ((size_t)tile0*16 + n16)*SS + q*8;
    if constexpr (BF) {
      xb0 = *(const short8*)((const u16*)x + base);
      xb1 = *(const short8*)((const u16*)x + base + 32);
    } else {
      const float* f = (const float*)x + base;
      xf0 = *(const floatx4*)f;       xf1 = *(const floatx4*)(f+4);
      xf2 = *(const floatx4*)(f+32);  xf3 = *(const floatx4*)(f+36);
    }
  }

  for (int i = 0; i < MW_TPW; ++i) {
    const int tau = tile0 + i;
    short8 xc0, xc1;
    if constexpr (BF) { xc0 = xb0; xc1 = xb1; }
    else              { xc0 = pack8(xf0, xf1); xc1 = pack8(xf2, xf3); }
    if (i + 1 < MW_TPW) {                        // prefetch next tile's x
      size_t base = ((size_t)(tau+1)*16 + n16)*SS + q*8;
      if constexpr (BF) {
        xb0 = *(const short8*)((const u16*)x + base);
        xb1 = *(const short8*)((const u16*)x + base + 32);
      } else {
        const float* f = (const float*)x + base;
        xf0 = *(const floatx4*)f;       xf1 = *(const floatx4*)(f+4);
        xf2 = *(const floatx4*)(f+32);  xf3 = *(const floatx4*)(f+36);
      }
    }
    // ---- layer 1: h1 = relu(W1@x+b1), all 128 cols, C-frag -> scratch --
#pragma unroll
    for (int j = 0; j < 8; ++j) {
      floatx4 a = {0.f,0.f,0.f,0.f};
      a = mfma(xc0, w1b[j][0], a);
      a = mfma(xc1, w1b[j][1], a);
#pragma unroll
      for (int r = 0; r < 4; ++r) {
        float v = a[r] + b1v[j]; v = v > 0.f ? v : 0.f;
        S[fragidx(4*q + r, 16*j + n16)] = f2bf(v);
      }
    }
    // ---- h1 A-frags (same-wave RAW: compiler inserts lgkmcnt) ----------
    short8 h1a0 = *(const short8*)(S + 0*512 + lane*8);
    short8 h1a1 = *(const short8*)(S + 1*512 + lane*8);
    short8 h1a2 = *(const short8*)(S + 2*512 + lane*8);
    short8 h1a3 = *(const short8*)(S + 3*512 + lane*8);
    // ---- layer 2: h2 = relu(W2@h1+b2) -> scratch (reuse after reads) ---
#pragma unroll
    for (int j = 0; j < 8; ++j) {
      floatx4 a = {0.f,0.f,0.f,0.f};
      a = mfma(h1a0, *(const short8*)&W2L[(size_t)((j*4+0)*64 + lane)*8], a);
      a = mfma(h1a1, *(const short8*)&W2L[(size_t)((j*4+1)*64 + lane)*8], a);
      a = mfma(h1a2, *(const short8*)&W2L[(size_t)((j*4+2)*64 + lane)*8], a);
      a = mfma(h1a3, *(const short8*)&W2L[(size_t)((j*4+3)*64 + lane)*8], a);
#pragma unroll
      for (int r = 0; r < 4; ++r) {
        float v = a[r] + b2v[j]; v = v > 0.f ? v : 0.f;
        S[fragidx(4*q + r, 16*j + n16)] = f2bf(v);
      }
    }
    // ---- dump tile (A-frag order), 64 B/lane coalesced -----------------
    {
      const u16* src = S + lane*32;
      u16* dst = h2g + (size_t)tau*2048 + lane*32;
      short8 d0 = *(const short8*)(src);
      short8 d1 = *(const short8*)(src + 8);
      short8 d2 = *(const short8*)(src + 16);
      short8 d3 = *(const short8*)(src + 24);
      *(short8*)(dst)      = d0;
      *(short8*)(dst + 8)  = d1;
      *(short8*)(dst + 16) = d2;
      *(short8*)(dst + 24) = d3;
    }
  }
}

// ---------------------------------------------------------------------------
// K2 (R6-proven, 501us): GRU scan, MLP removed. Per step: haf LDS reads,
// stage3 (Wih on h2 A-frag streamed from global, 2-step reg prefetch), rec,
// heads, ONE barrier. UNCHANGED.
// ---------------------------------------------------------------------------
template<bool BF>
__global__ __launch_bounds__(512, 2) void k_scan_split(
    const void* __restrict__ done_, const void* __restrict__ gstate,
    const void* __restrict__ Wih, const void* __restrict__ bih,
    const void* __restrict__ Whh, const void* __restrict__ bhh,
    const void* __restrict__ Wa, const void* __restrict__ ba,
    const void* __restrict__ Wc, const void* __restrict__ bc,
    const void* __restrict__ W1,                   // dtype detector only
    const u16* __restrict__ h2g,
    float* __restrict__ lgws, float* __restrict__ vws,
    void* __restrict__ out)
{
  if (buf_is_bf16((const u16*)W1) != BF) return;

  const int tid = threadIdx.x, lane = tid & 63, wv = tid >> 6;
  const int n16 = lane & 15, q = lane >> 4;
  const int b0 = blockIdx.x * 16, bx = blockIdx.x;
  const int jj = 16*wv + n16;

  __shared__ __align__(16) u16 hbuf[2][2048];   // double-buffered h A-frag

  // ---- weights -> register B-fragments ---------------------------------
  short8 wif[3][4], whf[3][4], scf[4];
  float bihv2, bhv2, bb0, bb1;
  {
    float bi0, bi1, bh0, bh1;
#pragma unroll
    for (int g = 0; g < 3; ++g) {
      int grow = g*128 + jj;
#pragma unroll
      for (int ks = 0; ks < 4; ++ks) {
        wif[g][ks] = ld8<BF>(Wih, (size_t)grow*HH + ks*32 + q*8);
        whf[g][ks] = ld8<BF>(Whh, (size_t)grow*HH + ks*32 + q*8);
      }
      float bi = ld1<BF>(bih, grow), bh = ld1<BF>(bhh, grow);
      if (g == 0) { bi0 = bi; bh0 = bh; }
      else if (g == 1) { bi1 = bi; bh1 = bh; }
      else { bihv2 = bi; bhv2 = bh; }
    }
    bb0 = bi0 + bh0;
    bb1 = bi1 + bh1;
  }
  if (wv == 1) {
#pragma unroll
    for (int ks = 0; ks < 4; ++ks) scf[ks] = ld8<BF>(Wa, (size_t)n16*HH + ks*32 + q*8);
  } else if (wv == 2) {
#pragma unroll
    for (int ks = 0; ks < 4; ++ks) {
      short8 z = {0,0,0,0,0,0,0,0};
      if (n16 == 0) z = ld8<BF>(Wc, (size_t)ks*32 + q*8);
      scf[ks] = z;
    }
  } else {
#pragma unroll
    for (int ks = 0; ks < 4; ++ks) { short8 z = {0,0,0,0,0,0,0,0}; scf[ks] = z; }
  }
  const float bav = ld1<BF>(ba, n16);
  const float bcv = ld1<BF>(bc, 0);

  // ---- h0 state --------------------------------------------------------
  float hreg[4];
#pragma unroll
  for (int r = 0; r < 4; ++r) {
    hreg[r] = ld1<BF>(gstate, (size_t)(b0 + 4*q + r)*HH + jj);
    hbuf[0][fragidx(4*q + r, jj)] = f2bf(hreg[r]);
  }
  float s4cur[2][4];
#pragma unroll
  for (int s = 0; s < 2; ++s)
#pragma unroll
    for (int r = 0; r < 4; ++r)
      s4cur[s][r] = 1.f - ld1<BF>(done_, (size_t)s*BB + b0 + 4*q + r);
  u32x2 draw[2];  floatx4 fdraw[2];
#pragma unroll
  for (int s = 0; s < 2; ++s) { draw[s].x = draw[s].y = 0; fdraw[s] = floatx4{0,0,0,0}; }

  // ---- h2 frag prefetch (2-deep register double buffer) ----------------
  const u16* const hz = h2g + (size_t)bx*2048;      // tile(t) = t*64 + bx
  short8 h2p[2][4];
#pragma unroll
  for (int ks = 0; ks < 4; ++ks)
    h2p[0][ks] = *(const short8*)(hz + (size_t)0*64*2048 + ks*512 + lane*8);
#pragma unroll
  for (int ks = 0; ks < 4; ++ks)
    h2p[1][ks] = *(const short8*)(hz + (size_t)1*64*2048 + ks*512 + lane*8);
  floatx4 pipe[3];
#pragma unroll
  for (int g = 0; g < 3; ++g) {            // stage3(tile 0) -> pipe for rec(0)
    floatx4 a = {0.f,0.f,0.f,0.f};
#pragma unroll
    for (int ks = 0; ks < 4; ++ks) a = mfma(h2p[0][ks], wif[g][ks], a);
    pipe[g] = a;
  }
#pragma unroll
  for (int ks = 0; ks < 4; ++ks)           // tile 2 into buffer 0
    h2p[0][ks] = *(const short8*)(hz + (size_t)2*64*2048 + ks*512 + lane*8);
  __syncthreads();

  u16* hw0 = &hbuf[1][0] + fragidx(4*q, jj);   // even step writes hbuf[1]
  u16* hw1 = &hbuf[0][0] + fragidx(4*q, jj);   // odd  step writes hbuf[0]

  for (int t0 = 0; t0 < TT; t0 += 2) {
#pragma unroll
    for (int s = 0; s < 2; ++s) {
      const int t = t0 + s;
      const int pw = s;                    // t0 even => t&1 == s (static!)
      const int pb = s ^ 1;                // (t+1)&1 -- h2p buffer parity

      // 1) critical h reads first
      short8 haf[4];
#pragma unroll
      for (int ks = 0; ks < 4; ++ks)
        haf[ks] = *(const short8*)(&hbuf[pw][0] + ks*512 + lane*8);

      // 2) stage3: gx(tile t+1) from h2p[pb] (fills haf read latency)
      floatx4 pn[3];
#pragma unroll
      for (int g = 0; g < 3; ++g) {
        floatx4 a = {0.f,0.f,0.f,0.f};
#pragma unroll
        for (int ks = 0; ks < 4; ++ks) a = mfma(h2p[pb][ks], wif[g][ks], a);
        pn[g] = a;
      }
      // 3) refill: tile t+3 (clamped; redundant at tail, never consumed)
      {
        const int tl = (t+3 < TT) ? t+3 : TT-1;
        const u16* tp = hz + (size_t)tl*64*2048;
#pragma unroll
        for (int ks = 0; ks < 4; ++ks)
          h2p[pb][ks] = *(const short8*)(tp + ks*512 + lane*8);
      }

      // 4) head for t-1 (fire-and-forget)
      if (t > 0 && (wv == 1 || wv == 2)) {
        floatx4 a = {0.f,0.f,0.f,0.f};
#pragma unroll
        for (int ks = 0; ks < 4; ++ks) a = mfma(haf[ks], scf[ks], a);
        if (wv == 1) {
#pragma unroll
          for (int r = 0; r < 4; ++r)
            lgws[((size_t)(t-1)*BB + b0 + 4*q + r)*16 + n16] = a[r] + bav;
        } else if (n16 == 0) {
#pragma unroll
          for (int r = 0; r < 4; ++r)
            vws[(size_t)(t-1)*BB + b0 + 4*q + r] = a[r] + bcv;
        }
      }

      // 5) recurrence step t
      floatx4 agh[3];
#pragma unroll
      for (int g = 0; g < 3; ++g) {
        floatx4 a = {0.f,0.f,0.f,0.f};
#pragma unroll
        for (int ks = 0; ks < 4; ++ks) a = mfma(haf[ks], whf[g][ks], a);
        agh[g] = a;
      }
      u16* hw = pw ? hw1 : hw0;
#pragma unroll
      for (int r = 0; r < 4; ++r) {
        float s4 = s4cur[s][r];
        float tr = pipe[0][r] + __builtin_fmaf(s4, agh[0][r], bb0);
        float tz = pipe[1][r] + __builtin_fmaf(s4, agh[1][r], bb1);
        float xn_ = pipe[2][r] + bihv2;
        float hn_ = __builtin_fmaf(s4, agh[2][r], bhv2);
        float rg = frcp(1.f + __expf(-tr));
        float zg = frcp(1.f + __expf(-tz));
        float ni = __builtin_fmaf(rg, hn_, xn_);
        float ng = __builtin_fmaf(2.f, frcp(1.f + __expf(-2.f*ni)), -1.f);  // tanh
        float hold = hreg[r] * s4;
        float hnew = __builtin_fmaf(zg, hold - ng, ng);
        hreg[r] = hnew;
        hw[r*8] = f2bf(hnew);
      }

      // 6) done prefetch (per 2 steps; clamped at tail)
      if (s == 0) {
#pragma unroll
        for (int ss = 0; ss < 2; ++ss) {
          const int tl = (t0+2+ss < TT) ? t0+2+ss : TT-1;
          size_t didx = (size_t)tl*BB + b0 + 4*q;
          if constexpr (BF) draw[ss] = *(const u32x2*)((const u16*)done_ + didx);
          else              fdraw[ss] = *(const floatx4*)((const float*)done_ + didx);
        }
      }

      barrier_lds();                        // the ONE barrier per step
      // 7) rotate gx pipe
#pragma unroll
      for (int g = 0; g < 3; ++g) pipe[g] = pn[g];
    }
    // rotate done regs (tail values unused)
    if constexpr (BF) {
#pragma unroll
      for (int ss = 0; ss < 2; ++ss) {
        s4cur[ss][0] = 1.f - bf2f((u16)(draw[ss].x & 0xFFFF));
        s4cur[ss][1] = 1.f - bf2f((u16)(draw[ss].x >> 16));
        s4cur[ss][2] = 1.f - bf2f((u16)(draw[ss].y & 0xFFFF));
        s4cur[ss][3] = 1.f - bf2f((u16)(draw[ss].y >> 16));
      }
    } else {
#pragma unroll
      for (int ss = 0; ss < 2; ++ss)
#pragma unroll
        for (int r = 0; r < 4; ++r) s4cur[ss][r] = 1.f - fdraw[ss][r];
    }
  }

  // epilogue: head for t=511 (h_511 in hbuf[0]) + h_last output
  {
    if (wv == 1 || wv == 2) {
      short8 haf[4];
#pragma unroll
      for (int ks = 0; ks < 4; ++ks) haf[ks] = *(const short8*)(&hbuf[0][0] + ks*512 + lane*8);
      floatx4 a = {0.f,0.f,0.f,0.f};
#pragma unroll
      for (int ks = 0; ks < 4; ++ks) a = mfma(haf[ks], scf[ks], a);
      if (wv == 1) {
#pragma unroll
        for (int r = 0; r < 4; ++r)
          lgws[((size_t)(TT-1)*BB + b0 + 4*q + r)*16 + n16] = a[r] + bav;
      } else if (n16 == 0) {
#pragma unroll
        for (int r = 0; r < 4; ++r)
          vws[(size_t)(TT-1)*BB + b0 + 4*q + r] = a[r] + bcv;
      }
    }
#pragma unroll
    for (int r = 0; r < 4; ++r)
      st1<BF>(out, (size_t)3*TBR + (size_t)(b0 + 4*q + r)*HH + jj, hreg[r]);
  }
}

// ---------------------------------------------------------------------------
// Deep fallback (R5 mono) if workspace can't hold h2g. UNCHANGED.
// ---------------------------------------------------------------------------
template<bool BF>
__global__ __launch_bounds__(512, 2) void k_scan_mono(
    const void* __restrict__ x, const void* __restrict__ done_,
    const void* __restrict__ gstate,
    const void* __restrict__ W1, const void* __restrict__ b1,
    const void* __restrict__ W2, const void* __restrict__ b2,
    const void* __restrict__ Wih, const void* __restrict__ bih,
    const void* __restrict__ Whh, const void* __restrict__ bhh,
    const void* __restrict__ Wa, const void* __restrict__ ba,
    const void* __restrict__ Wc, const void* __restrict__ bc,
    float* __restrict__ lgws, float* __restrict__ vws,
    void* __restrict__ out)
{
  if (buf_is_bf16((const u16*)W1) != BF) return;

  const int tid = threadIdx.x, lane = tid & 63, wv = tid >> 6;
  const int n16 = lane & 15, q = lane >> 4;
  const int b0 = blockIdx.x * 16;
  const int jj = 16*wv + n16;

  __shared__ __align__(16) u16 hbuf[2][2048];
  __shared__ __align__(16) u16 h1f[2][2048];
  __shared__ __align__(16) u16 h2f[2][2048];

  short8 w1f[2], w2f[4], wif[3][4], whf[3][4], scf[4];
  float b1v, b2v, bihv2, bhv2, bb0, bb1;
  {
    int row = wv*16 + n16;
#pragma unroll
    for (int ks = 0; ks < 2; ++ks) w1f[ks] = ld8<BF>(W1, (size_t)row*SS + ks*32 + q*8);
    b1v = ld1<BF>(b1, row);
#pragma unroll
    for (int ks = 0; ks < 4; ++ks) w2f[ks] = ld8<BF>(W2, (size_t)row*HH + ks*32 + q*8);
    b2v = ld1<BF>(b2, row);
    float bi0, bi1, bh0, bh1;
#pragma unroll
    for (int g = 0; g < 3; ++g) {
      int grow = g*128 + jj;
#pragma unroll
      for (int ks = 0; ks < 4; ++ks) {
        wif[g][ks] = ld8<BF>(Wih, (size_t)grow*HH + ks*32 + q*8);
        whf[g][ks] = ld8<BF>(Whh, (size_t)grow*HH + ks*32 + q*8);
      }
      float bi = ld1<BF>(bih, grow), bh = ld1<BF>(bhh, grow);
      if (g == 0) { bi0 = bi; bh0 = bh; }
      else if (g == 1) { bi1 = bi; bh1 = bh; }
      else { bihv2 = bi; bhv2 = bh; }
    }
    bb0 = bi0 + bh0;
    bb1 = bi1 + bh1;
  }
  if (wv == 1) {
#pragma unroll
    for (int ks = 0; ks < 4; ++ks) scf[ks] = ld8<BF>(Wa, (size_t)n16*HH + ks*32 + q*8);
  } else if (wv == 2) {
#pragma unroll
    for (int ks = 0; ks < 4; ++ks) {
      short8 z = {0,0,0,0,0,0,0,0};
      if (n16 == 0) z = ld8<BF>(Wc, (size_t)ks*32 + q*8);
      scf[ks] = z;
    }
  } else {
#pragma unroll
    for (int ks = 0; ks < 4; ++ks) { short8 z = {0,0,0,0,0,0,0,0}; scf[ks] = z; }
  }
  const float bav = ld1<BF>(ba, n16);
  const float bcv = ld1<BF>(bc, 0);

  float hreg[4];
#pragma unroll
  for (int r = 0; r < 4; ++r) {
    hreg[r] = ld1<BF>(gstate, (size_t)(b0 + 4*q + r)*HH + jj);
    hbuf[0][fragidx(4*q + r, jj)] = f2bf(hreg[r]);
  }
  short8 xc[2][2], xn[2][2];
#pragma unroll
  for (int s = 0; s < 2; ++s)
#pragma unroll
    for (int ks = 0; ks < 2; ++ks)
      xc[s][ks] = ld8<BF>(x, ((size_t)s*BB + b0 + n16)*SS + ks*32 + q*8);
  float s4cur[2][4];
#pragma unroll
  for (int s = 0; s < 2; ++s)
#pragma unroll
    for (int r = 0; r < 4; ++r) s4cur[s][r] = 1.f;
  u32x2 draw[2];  floatx4 fdraw[2];
#pragma unroll
  for (int s = 0; s < 2; ++s) { draw[s].x = draw[s].y = 0; fdraw[s] = floatx4{0,0,0,0}; }
#pragma unroll
  for (int s = 0; s < 2; ++s)
#pragma unroll
    for (int ks = 0; ks < 2; ++ks) { short8 z={0,0,0,0,0,0,0,0}; xn[s][ks]=z; }
  floatx4 pipe[2][3];
#pragma unroll
  for (int s = 0; s < 2; ++s)
#pragma unroll
    for (int g = 0; g < 3; ++g) pipe[s][g] = floatx4{0.f,0.f,0.f,0.f};
  __syncthreads();

  u16* hw0 = &hbuf[1][0] + fragidx(4*q, jj);
  u16* hw1 = &hbuf[0][0] + fragidx(4*q, jj);

  auto iter = [&](int t0, auto steady) {
    constexpr bool ST = decltype(steady)::value;
#pragma unroll
    for (int s = 0; s < 2; ++s) {
      const int t = t0 + s;
      const bool s1on = ST || (t <= TT-5);
      const bool s2on = ST || (t >= -3 && t <= TT-4);
      const bool s3on = ST || (t >= -2 && t <= TT-3);
      const bool ron  = ST || (t >= 0);
      const int pw = t & 1;

      short8 haf[4];
      if (ron) {
#pragma unroll
        for (int ks = 0; ks < 4; ++ks)
          haf[ks] = *(const short8*)(&hbuf[pw][0] + ks*512 + lane*8);
      }
      if (s1on) {
        floatx4 a = {0.f,0.f,0.f,0.f};
        a = mfma(xc[s][0], w1f[0], a);
        a = mfma(xc[s][1], w1f[1], a);
#pragma unroll
        for (int r = 0; r < 4; ++r) {
          float v = a[r] + b1v; v = v > 0.f ? v : 0.f;
          h1f[pw][fragidx(4*q + r, jj)] = f2bf(v);
        }
      }
      if (s2on) {
        short8 h1a[4];
#pragma unroll
        for (int ks = 0; ks < 4; ++ks)
          h1a[ks] = *(const short8*)(&h1f[pw^1][0] + ks*512 + lane*8);
        floatx4 a = {0.f,0.f,0.f,0.f};
#pragma unroll
        for (int ks = 0; ks < 4; ++ks) a = mfma(h1a[ks], w2f[ks], a);
#pragma unroll
        for (int r = 0; r < 4; ++r) {
          float v = a[r] + b2v; v = v > 0.f ? v : 0.f;
          h2f[pw][fragidx(4*q + r, jj)] = f2bf(v);
        }
      }
      if (s == 0) {
        if (ST || (t0 + 6 < TT)) {
          if constexpr (BF) {
#pragma unroll
            for (int ss = 0; ss < 2; ++ss) {
              size_t base = ((size_t)(t0+6+ss)*BB + b0 + n16)*SS + q*8;
              xn[ss][0] = *(const short8*)((const u16*)x + base);
              xn[ss][1] = *(const short8*)((const u16*)x + base + 32);
            }
          }
        }
        if (ST || (t0+2 >= 0 && t0+2 < TT)) {
#pragma unroll
          for (int ss = 0; ss < 2; ++ss) {
            size_t didx = (size_t)(t0+2+ss)*BB + b0 + 4*q;
            if constexpr (BF) draw[ss] = *(const u32x2*)((const u16*)done_ + didx);
            else              fdraw[ss] = *(const floatx4*)((const float*)done_ + didx);
          }
        }
      }
      if (ron) {
        if (t > 0 && (wv == 1 || wv == 2)) {
          floatx4 a = {0.f,0.f,0.f,0.f};
#pragma unroll
          for (int ks = 0; ks < 4; ++ks) a = mfma(haf[ks], scf[ks], a);
          if (wv == 1) {
#pragma unroll
            for (int r = 0; r < 4; ++r)
              lgws[((size_t)(t-1)*BB + b0 + 4*q + r)*16 + n16] = a[r] + bav;
          } else if (n16 == 0) {
#pragma unroll
            for (int r = 0; r < 4; ++r)
              vws[(size_t)(t-1)*BB + b0 + 4*q + r] = a[r] + bcv;
          }
        }
        floatx4 agh[3];
#pragma unroll
        for (int g = 0; g < 3; ++g) {
          floatx4 a = {0.f,0.f,0.f,0.f};
#pragma unroll
          for (int ks = 0; ks < 4; ++ks) a = mfma(haf[ks], whf[g][ks], a);
          agh[g] = a;
        }
        u16* hw = pw ? hw1 : hw0;
#pragma unroll
        for (int r = 0; r < 4; ++r) {
          float s4 = s4cur[s][r];
          float tr = pipe[s][0][r] + __builtin_fmaf(s4, agh[0][r], bb0);
          float tz = pipe[s][1][r] + __builtin_fmaf(s4, agh[1][r], bb1);
          float xn_ = pipe[s][2][r] + bihv2;
          float hn_ = __builtin_fmaf(s4, agh[2][r], bhv2);
          float rg = frcp(1.f + __expf(-tr));
          float zg = frcp(1.f + __expf(-tz));
          float ni = __builtin_fmaf(rg, hn_, xn_);
          float ng = __builtin_fmaf(2.f, frcp(1.f + __expf(-2.f*ni)), -1.f);
          float hold = hreg[r] * s4;
          float hnew = __builtin_fmaf(zg, hold - ng, ng);
          hreg[r] = hnew;
          hw[r*8] = f2bf(hnew);
        }
      }
      if (s3on) {
        short8 h2a[4];
#pragma unroll
        for (int ks = 0; ks < 4; ++ks)
          h2a[ks] = *(const short8*)(&h2f[pw^1][0] + ks*512 + lane*8);
#pragma unroll
        for (int g = 0; g < 3; ++g) {
          floatx4 a = {0.f,0.f,0.f,0.f};
#pragma unroll
          for (int ks = 0; ks < 4; ++ks) a = mfma(h2a[ks], wif[g][ks], a);
          pipe[s][g] = a;
        }
      }
      barrier_lds();
    }
    if (ST || (t0 + 6 < TT)) {
      if constexpr (BF) {
#pragma unroll
        for (int ss = 0; ss < 2; ++ss) { xc[ss][0] = xn[ss][0]; xc[ss][1] = xn[ss][1]; }
      } else {
#pragma unroll
        for (int ss = 0; ss < 2; ++ss) {
          size_t base = ((size_t)(t0+6+ss)*BB + b0 + n16)*SS + q*8;
          xc[ss][0] = ld8<false>(x, base);
          xc[ss][1] = ld8<false>(x, base + 32);
        }
      }
    }
    if (ST || (t0+2 >= 0 && t0+2 < TT)) {
      if constexpr (BF) {
#pragma unroll
        for (int ss = 0; ss < 2; ++ss) {
          s4cur[ss][0] = 1.f - bf2f((u16)(draw[ss].x & 0xFFFF));
          s4cur[ss][1] = 1.f - bf2f((u16)(draw[ss].x >> 16));
          s4cur[ss][2] = 1.f - bf2f((u16)(draw[ss].y & 0xFFFF));
          s4cur[ss][3] = 1.f - bf2f((u16)(draw[ss].y >> 16));
        }
      } else {
#pragma unroll
        for (int ss = 0; ss < 2; ++ss)
#pragma unroll
          for (int r = 0; r < 4; ++r) s4cur[ss][r] = 1.f - fdraw[ss][r];
      }
    }
  };

  iter(-4, FalseT{});
  iter(-2, FalseT{});
  for (int t0 = 0; t0 <= TT - 8; t0 += 2) iter(t0, TrueT{});
  iter(TT-6, FalseT{});
  iter(TT-4, FalseT{});
  iter(TT-2, FalseT{});

  {
    if (wv == 1 || wv == 2) {
      short8 haf[4];
#pragma unroll
      for (int ks = 0; ks < 4; ++ks) haf[ks] = *(const short8*)(&hbuf[0][0] + ks*512 + lane*8);
      floatx4 a = {0.f,0.f,0.f,0.f};
#pragma unroll
      for (int ks = 0; ks < 4; ++ks) a = mfma(haf[ks], scf[ks], a);
      if (wv == 1) {
#pragma unroll
        for (int r = 0; r < 4; ++r)
          lgws[((size_t)(TT-1)*BB + b0 + 4*q + r)*16 + n16] = a[r] + bav;
      } else if (n16 == 0) {
#pragma unroll
        for (int r = 0; r < 4; ++r)
          vws[(size_t)(TT-1)*BB + b0 + 4*q + r] = a[r] + bcv;
      }
    }
#pragma unroll
    for (int r = 0; r < 4; ++r)
      st1<BF>(out, (size_t)3*TBR + (size_t)(b0 + 4*q + r)*HH + jj, hreg[r]);
  }
}

// ---------------------------------------------------------------------------
// K3: data-parallel head finisher (unchanged).
// ---------------------------------------------------------------------------
template<bool BF>
__global__ __launch_bounds__(256) void k_head(
    const float* __restrict__ lgws, const float* __restrict__ vws,
    const int* __restrict__ action, const void* __restrict__ W1,
    void* __restrict__ out)
{
  if (buf_is_bf16((const u16*)W1) != BF) return;
  size_t row = (size_t)blockIdx.x * 256 + threadIdx.x;
  if (row >= (size_t)TBR) return;
  const float* lp = lgws + row*16;
  floatx4 v[4];
#pragma unroll
  for (int i = 0; i < 4; ++i) v[i] = *(const floatx4*)(lp + 4*i);
  float mx = v[0][0];
#pragma unroll
  for (int i = 0; i < 4; ++i)
#pragma unroll
    for (int j = 0; j < 4; ++j) mx = fmaxf(mx, v[i][j]);
  float sum = 0.f, se = 0.f;
#pragma unroll
  for (int i = 0; i < 4; ++i)
#pragma unroll
    for (int j = 0; j < 4; ++j) {
      float d = v[i][j] - mx;
      float e = __expf(d);
      sum += e; se = __builtin_fmaf(e, d, se);
    }
  float ls = __logf(sum);
  int a = action[row];
  float la = lp[a];
  float lpa = (la - mx) - ls;
  float ent = ls - se * frcp(sum);
  st1<BF>(out, row*3,     lpa);
  st1<BF>(out, row*3 + 1, ent);
  st1<BF>(out, row*3 + 2, vws[row]);
}

// ---------------------------------------------------------------------------
extern "C" void kernel_launch(void* const* d_in, const int* in_sizes, int n_in,
                              void* d_out, int out_size, void* d_ws, size_t ws_size,
                              hipStream_t stream) {
  const void* x    = d_in[0];
  const void* done = d_in[1];
  const int*  act  = (const int*)d_in[2];
  const void* gst  = d_in[3];
  const void* W1   = d_in[4];
  const void* b1   = d_in[5];
  const void* W2   = d_in[6];
  const void* b2   = d_in[7];
  const void* Wih  = d_in[8];
  const void* bih  = d_in[9];
  const void* Whh  = d_in[10];
  const void* bhh  = d_in[11];
  const void* Wa   = d_in[12];
  const void* ba   = d_in[13];
  const void* Wc   = d_in[14];
  const void* bc   = d_in[15];

  float* lgws = (float*)d_ws;                       // [TBR,16] fp32 = 33.6 MB
  float* vws  = lgws + (size_t)16*TBR;              // [TBR]    fp32 =  2.1 MB
  u16*   h2g  = (u16*)(vws + (size_t)TBR);          // [NTILE,2048] bf16 frag = 134 MB
  const size_t need = (size_t)(16*TBR + TBR)*4 + (size_t)NTILE*4096;

  if (ws_size >= need) {
    hipLaunchKernelGGL((k_mlp<true>),  dim3(MGRID), dim3(256), 0, stream,
                       x, W1, b1, W2, b2, h2g);
    hipLaunchKernelGGL((k_mlp<false>), dim3(MGRID), dim3(256), 0, stream,
                       x, W1, b1, W2, b2, h2g);
    hipLaunchKernelGGL((k_scan_split<true>),  dim3(64), dim3(512), 0, stream,
                       done, gst, Wih, bih, Whh, bhh, Wa, ba, Wc, bc,
                       W1, h2g, lgws, vws, d_out);
    hipLaunchKernelGGL((k_scan_split<false>), dim3(64), dim3(512), 0, stream,
                       done, gst, Wih, bih, Whh, bhh, Wa, ba, Wc, bc,
                       W1, h2g, lgws, vws, d_out);
  } else {
    hipLaunchKernelGGL((k_scan_mono<true>),  dim3(64), dim3(512), 0, stream,
                       x, done, gst, W1, b1, W2, b2, Wih, bih,
                       Whh, bhh, Wa, ba, Wc, bc, lgws, vws, d_out);
    hipLaunchKernelGGL((k_scan_mono<false>), dim3(64), dim3(512), 0, stream,
                       x, done, gst, W1, b1, W2, b2, Wih, bih,
                       Whh, bhh, Wa, ba, Wc, bc, lgws, vws, d_out);
  }
  hipLaunchKernelGGL((k_head<true>),  dim3(TBR/256), dim3(256), 0, stream,
                     lgws, vws, act, W1, d_out);
  hipLaunchKernelGGL((k_head<false>), dim3(TBR/256), dim3(256), 0, stream,
                     lgws, vws, act, W1, d_out);
}